// Round 1
// baseline (290.052 us; speedup 1.0000x reference)
//
#include <hip/hip_runtime.h>
#include <hip/hip_cooperative_groups.h>
#include <math.h>

namespace cg = cooperative_groups;

#define IH 1024
#define IW 1024
#define NPIX (IH * IW)
#define NW 16   // chunks
#define CH 64   // rows per chunk
#define WB 4    // worker blocks in fused kernel (NW/4 chunks each)

// async global->LDS: 64 lanes x 4B = 256 B = TWO consecutive 32-word rows
__device__ __forceinline__ void dma4(const unsigned int* g, unsigned int* l) {
    __builtin_amdgcn_global_load_lds(
        (const __attribute__((address_space(1))) void*)g,
        (__attribute__((address_space(3))) void*)l, 4, 0, 0);
}

// One row of the recurrence (verified absmax 0 since R8).
#define CHAIN_STEP(W_, S_, T_)                                                  \
    unsigned int hxp = (prevU << 1) | prevU | ((prevU >> 1) | crp);             \
    unsigned int seed = hxp | (T_);                                             \
    unsigned int P = (W_);                                                      \
    unsigned int G = (S_) | (P & seed);                                         \
    unsigned int A = G | P;                                                     \
    unsigned int AXG = A ^ G;                                                   \
    unsigned int s1v = A + G;                                                   \
    unsigned long long gm = __ballot(s1v < A) & 0xFFFFFFFFull;                  \
    unsigned long long pm = __ballot(s1v == 0xFFFFFFFFu) & 0xFFFFFFFFull;       \
    unsigned long long G0 = __ballot((G & 1u) != 0u);                           \
    unsigned long long P0 = __ballot((P & 1u) != 0u);                           \
    unsigned long long aa = gm | pm;                                            \
    unsigned long long ssum = aa + gm;                                          \
    unsigned long long cvw = ssum ^ aa ^ gm;                                    \
    unsigned long long mlo_o = G0 | (P0 & cvw);                                 \
    unsigned int cin = (((unsigned int)cvw) >> k) & 1u;                         \
    unsigned int ovb = ((((unsigned int)(cvw >> 1)) >> k) & 1u) << 31;          \
    unsigned int s2 = s1v + cin;                                                \
    unsigned int outv = ((s2 ^ AXG) >> 1) | ovb;                                \
    unsigned int rtP = ((((unsigned int)(mlo_o >> 1)) >> k) & 1u) << 31;        \
    crp = cin | rtP;                                                            \
    prevU = outv;

// STAT_r = Rx(S_r) | Hx(S_{r+1})  (verified)
#define MKT(T_, SA_, SN_) {                                                     \
    unsigned long long mla = __ballot(((SA_) & 1u) != 0u);                      \
    unsigned long long mln = __ballot(((SN_) & 1u) != 0u);                      \
    unsigned long long mhn = __ballot(((SN_) >> 31) != 0u);                     \
    unsigned int rxC = (SA_) | ((SA_) >> 1)                                     \
                     | (((((unsigned int)(mla >> 1)) >> k) & 1u) << 31);        \
    unsigned int hxN = (SN_) | ((SN_) << 1) | ((SN_) >> 1)                      \
                     | ((((unsigned int)(mhn << 1)) >> k) & 1u)                 \
                     | (((((unsigned int)(mln >> 1)) >> k) & 1u) << 31);        \
    T_ = rxC | hxN; }

// Spec row: bits only (R12: no float output from 16 waves). Ring indexed by wv.
#define SPEC_ROW(dd) {                                                          \
    const int d = (dd);                                                         \
    const int r = r0 + d;                                                       \
    unsigned int Wv = ringW[wv][d & 7][k];                                      \
    unsigned int RS = (d < 63) ? ringS[wv][(d + 1) & 7][k] : Stail;             \
    unsigned long long mhiN = __ballot((RS >> 31) != 0u);                       \
    unsigned long long mloN = __ballot((RS & 1u) != 0u);                        \
    unsigned int rxC = SA | (SA >> 1)                                           \
                     | (((((unsigned int)(mloA >> 1)) >> k) & 1u) << 31);       \
    unsigned int hxN = RS | (RS << 1) | (RS >> 1)                               \
                     | ((((unsigned int)(mhiN << 1)) >> k) & 1u)                \
                     | (((((unsigned int)(mloN >> 1)) >> k) & 1u) << 31);       \
    unsigned int Tv = rxC | hxN;                                                \
    CHAIN_STEP(Wv, SA, Tv)                                                      \
    if (r <= 1022) Osp[r * 32 + k] = outv;                                      \
    SA = RS; mloA = mloN;                                                       \
}

#define FIX_STEP(d, W_, S_, T_, SP_) if (!done) {                               \
    const int r = r0 + (d);                                                     \
    CHAIN_STEP(W_, S_, T_)                                                      \
    unsigned long long df = __ballot(outv != (SP_));                            \
    if ((df & 0xFFFFFFFFull) == 0ull) { done = true; converged = true; }        \
    else Osp[r * 32 + k] = outv;                                                \
}

// =====================================================================
// Fused single-pass Canny: phase1 (gray/Sobel/NMS) -> grid.sync ->
// phase2 (spec+fix, 16 waves in 4 blocks, hybrid LDS/global token) ->
// grid.sync -> phase3 (unpack). Cooperative launch guarantees
// co-residency; agent fences around grid.sync handle XCD L2 coherence.
// =====================================================================
__global__ __launch_bounds__(256, 2) void k_canny(
        const float* __restrict__ x,
        unsigned long long* __restrict__ SpU,
        unsigned long long* __restrict__ WpU,
        unsigned int* __restrict__ Osp,
        float* __restrict__ out,
        unsigned int* __restrict__ gTok,
        unsigned int* __restrict__ gPrev) {
    __shared__ float g[20][72];
    __shared__ float m[18][68];
    __shared__ unsigned int ringW[4][8][32];
    __shared__ unsigned int ringS[4][8][32];
    __shared__ unsigned int prevLds[4][32];
    __shared__ unsigned int locTok;

    const int tid = threadIdx.x;
    if (tid == 0) locTok = 0u;   // ordered before phase2 by phase1 barriers

    // ---------------- phase 1: two tiles of gray -> Sobel -> NMS -> bits ----
    for (int tt = 0; tt < 2; ++tt) {
        const int tile = ((int)blockIdx.x << 1) + tt;
        const int bx = tile & 15, by = tile >> 4;
        const int gi0 = by * 16 - 2, gj0 = bx * 64 - 2;

        for (int e = tid; e < 20 * 68; e += 256) {
            int ly = e / 68, lx = e - ly * 68;
            int gy = gi0 + ly, gxc = gj0 + lx;
            float v = 0.f;
            if ((unsigned)gy < (unsigned)IH && (unsigned)gxc < (unsigned)IW) {
                int p = gy * IW + gxc;
                float r = x[p], gg = x[NPIX + p], b = x[2 * NPIX + p];
                v = __fadd_rn(__fadd_rn(__fmul_rn(r, 0.2989f), __fmul_rn(gg, 0.587f)),
                              __fmul_rn(b, 0.114f));
            }
            g[ly][lx] = v;
        }
        __syncthreads();

        for (int e = tid; e < 18 * 66; e += 256) {
            int ly = e / 66, lx = e - ly * 66;
            float a00 = g[ly][lx],   a01 = g[ly][lx+1],   a02 = g[ly][lx+2];
            float a10 = g[ly+1][lx],                      a12 = g[ly+1][lx+2];
            float a20 = g[ly+2][lx], a21 = g[ly+2][lx+1], a22 = g[ly+2][lx+2];
            float gx = __fmul_rn(-1.f, a00);
            gx = __fadd_rn(gx, a02);
            gx = __fadd_rn(gx, __fmul_rn(-2.f, a10));
            gx = __fadd_rn(gx, __fmul_rn(2.f, a12));
            gx = __fadd_rn(gx, __fmul_rn(-1.f, a20));
            gx = __fadd_rn(gx, a22);
            float gy = a00;
            gy = __fadd_rn(gy, __fmul_rn(2.f, a01));
            gy = __fadd_rn(gy, a02);
            gy = __fadd_rn(gy, __fmul_rn(-1.f, a20));
            gy = __fadd_rn(gy, __fmul_rn(-2.f, a21));
            gy = __fadd_rn(gy, __fmul_rn(-1.f, a22));
            m[ly][lx] = __fsqrt_rn(__fadd_rn(__fmul_rn(gx, gx), __fmul_rn(gy, gy)));
        }
        __syncthreads();

        {
            const int lane = tid & 63;
            const int wq = tid >> 6;
            #pragma unroll
            for (int rr = 0; rr < 4; ++rr) {
                int ti = wq * 4 + rr;
                int i = by * 16 + ti, j = bx * 64 + lane;
                float a00 = g[ti+1][lane+1], a01 = g[ti+1][lane+2], a02 = g[ti+1][lane+3];
                float a10 = g[ti+2][lane+1],                         a12 = g[ti+2][lane+3];
                float a20 = g[ti+3][lane+1], a21 = g[ti+3][lane+2], a22 = g[ti+3][lane+3];
                float gx = __fmul_rn(-1.f, a00);
                gx = __fadd_rn(gx, a02);
                gx = __fadd_rn(gx, __fmul_rn(-2.f, a10));
                gx = __fadd_rn(gx, __fmul_rn(2.f, a12));
                gx = __fadd_rn(gx, __fmul_rn(-1.f, a20));
                gx = __fadd_rn(gx, a22);
                float gy = a00;
                gy = __fadd_rn(gy, __fmul_rn(2.f, a01));
                gy = __fadd_rn(gy, a02);
                gy = __fadd_rn(gy, __fmul_rn(-1.f, a20));
                gy = __fadd_rn(gy, __fmul_rn(-2.f, a21));
                gy = __fadd_rn(gy, __fmul_rn(-1.f, a22));

                float ai = __fmul_rn(atan2f(gy, gx), 57.295779513082320876798154814105f);
                float c = m[ti+1][lane+1];
                float n1, n2;
                if (ai < -22.5f || ai >= 157.5f)      { n1 = m[ti+1][lane];   n2 = m[ti+1][lane+2]; }
                else if (ai < 22.5f)                  { n1 = m[ti][lane+1];   n2 = m[ti+2][lane+1]; }
                else if (ai < 67.5f)                  { n1 = m[ti][lane];     n2 = m[ti+2][lane+2]; }
                else if (ai < 112.5f)                 { n1 = m[ti][lane+1];   n2 = m[ti+2][lane+1]; }
                else                                  { n1 = m[ti][lane+2];   n2 = m[ti+2][lane];   }
                bool border = (i == 0) | (i == IH - 1) | (j == 0) | (j == IW - 1);
                bool keep = (c >= n1) && (c >= n2);
                float supp = keep ? c : 0.f;
                bool sb = !border && (supp >= 50.f);
                bool wb = !border && (supp >= 20.f) && !(supp >= 50.f);
                unsigned long long bs = __ballot(sb);
                unsigned long long bw = __ballot(wb);
                if (lane == 0) {
                    SpU[i * 16 + bx] = bs;
                    WpU[i * 16 + bx] = bw;
                }
            }
        }
        __syncthreads();   // g/m reused by next tile
    }

    __builtin_amdgcn_fence(__ATOMIC_RELEASE, "agent");
    cg::this_grid().sync();
    __builtin_amdgcn_fence(__ATOMIC_ACQUIRE, "agent");

    // ---------------- phase 2: spec + fix (blocks 0..3, 4 chunk-waves each) --
    if ((int)blockIdx.x < WB) {
        const int wv = tid >> 6;                 // wave in block, 0..3
        const int lane = tid & 63;
        const int k = lane & 31;
        const int c = ((int)blockIdx.x << 2) | wv;   // chunk 0..15
        const int r0 = c * CH + 1;
        const unsigned int* Sp = (const unsigned int*)SpU;
        const unsigned int* Wp = (const unsigned int*)WpU;

        // --- spec (verified structure; ring per wave, counted vmcnt) ---
        #pragma unroll
        for (int gq = 0; gq < 3; ++gq) {
            dma4(Wp + (r0 + 2 * gq) * 32 + lane, &ringW[wv][(2 * gq) & 7][0]);
            dma4(Sp + (r0 + 2 * gq) * 32 + lane, &ringS[wv][(2 * gq) & 7][0]);
        }
        unsigned int prevU = Sp[(r0 - 1) * 32 + k];   // static lower bound
        int tl = r0 + 64; if (tl > 1023) tl = 1023;
        unsigned int Stail = Sp[tl * 32 + k];
        unsigned int crp;
        {
            unsigned long long mh = __ballot((prevU >> 31) != 0u);
            unsigned long long ml = __ballot((prevU & 1u) != 0u);
            crp = ((((unsigned int)(mh << 1)) >> k) & 1u)
                | (((((unsigned int)(ml >> 1)) >> k) & 1u) << 31);
        }
        if (c == 0 && lane < 32) Osp[k] = 0u;
        if (c == NW - 1 && lane < 32) Osp[1023 * 32 + k] = 0u;

        asm volatile("s_waitcnt vmcnt(4)" ::: "memory");
        unsigned int SA = ringS[wv][0][k];
        unsigned long long mloA = __ballot((SA & 1u) != 0u);

        #pragma unroll 1
        for (int t = 0; t < 32; ++t) {
            if (t < 29) {
                int g2 = t + 3;
                dma4(Wp + (r0 + 2 * g2) * 32 + lane, &ringW[wv][(2 * g2) & 7][0]);
                dma4(Sp + (r0 + 2 * g2) * 32 + lane, &ringS[wv][(2 * g2) & 7][0]);
                asm volatile("s_waitcnt vmcnt(4)" ::: "memory");
            } else if (t == 29) {
                asm volatile("s_waitcnt vmcnt(2)" ::: "memory");
            } else {
                asm volatile("s_waitcnt vmcnt(0)" ::: "memory");
            }
            SPEC_ROW(2 * t)
            SPEC_ROW(2 * t + 1)
        }
        // drain last spec stores before re-reading Osp (same-wave st->ld hazard)
        asm volatile("s_waitcnt vmcnt(0)" ::: "memory");

        // --- prestage fix state (overlaps with token spin) ---
        const unsigned int* Sb = Sp + r0 * 32 + k;
        unsigned int S0 = Sb[0],   S1 = Sb[32],  S2 = Sb[64],  S3 = Sb[96],
                     S4 = Sb[128], S5 = Sb[160], S6 = Sb[192], S7 = Sb[224],
                     S8 = Sb[256];
        const unsigned int* Wb = Wp + r0 * 32 + k;
        unsigned int W0 = Wb[0],   W1 = Wb[32],  W2 = Wb[64],  W3 = Wb[96],
                     W4 = Wb[128], W5 = Wb[160], W6 = Wb[192], W7 = Wb[224];
        const unsigned int* Ob = Osp + r0 * 32 + k;
        unsigned int p0 = Ob[0],   p1 = Ob[32],  p2 = Ob[64],  p3 = Ob[96],
                     p4 = Ob[128], p5 = Ob[160], p6 = Ob[192], p7 = Ob[224];
        int lr = r0 + 63; if (lr > 1022) lr = 1022;
        unsigned int p1last = Osp[lr * 32 + k];
        unsigned int T0, T1, T2, T3, T4, T5, T6, T7;
        MKT(T0, S0, S1) MKT(T1, S1, S2) MKT(T2, S2, S3) MKT(T3, S3, S4)
        MKT(T4, S4, S5) MKT(T5, S5, S6) MKT(T6, S6, S7) MKT(T7, S7, S8)

        unsigned int bd = p1last;
        bool done = false, converged = false;
        prevU = 0u; crp = 0u;
        if (c > 0) {
            if (wv == 0) {   // cross-block handoff (3 of these total)
                while (__hip_atomic_load(gTok, __ATOMIC_ACQUIRE,
                                         __HIP_MEMORY_SCOPE_AGENT)
                       != (unsigned int)blockIdx.x)
                    __builtin_amdgcn_s_sleep(1);
                prevU = __hip_atomic_load(&gPrev[k], __ATOMIC_RELAXED,
                                          __HIP_MEMORY_SCOPE_AGENT);
            } else {          // intra-block handoff (verified k_fix pattern)
                while (*((volatile unsigned int*)&locTok) != (unsigned int)wv)
                    __builtin_amdgcn_s_sleep(1);
                asm volatile("" ::: "memory");
                prevU = prevLds[wv][k];
            }
            {
                unsigned long long mh = __ballot((prevU >> 31) != 0u);
                unsigned long long ml = __ballot((prevU & 1u) != 0u);
                crp = ((((unsigned int)(mh << 1)) >> k) & 1u)
                    | (((((unsigned int)(ml >> 1)) >> k) & 1u) << 31);
            }
            FIX_STEP(0, W0, S0, T0, p0) FIX_STEP(1, W1, S1, T1, p1)
            FIX_STEP(2, W2, S2, T2, p2) FIX_STEP(3, W3, S3, T3, p3)
            FIX_STEP(4, W4, S4, T4, p4) FIX_STEP(5, W5, S5, T5, p5)
            FIX_STEP(6, W6, S6, T6, p6) FIX_STEP(7, W7, S7, T7, p7)
            if (!done) {
                #pragma unroll 1
                for (int d = 8; d < CH; ++d) {    // rare deep path
                    int r = r0 + d;
                    if (r > 1022) break;
                    unsigned int Wv = Wp[r * 32 + k];
                    unsigned int Sv = Sp[r * 32 + k];
                    int rn = r + 1; if (rn > 1023) rn = 1023;
                    unsigned int Sn = Sp[rn * 32 + k];
                    unsigned int sp = Osp[r * 32 + k];
                    unsigned int Tv;
                    MKT(Tv, Sv, Sn)
                    CHAIN_STEP(Wv, Sv, Tv)
                    unsigned long long df = __ballot(outv != sp);
                    if ((df & 0xFFFFFFFFull) == 0ull) { converged = true; break; }
                    Osp[r * 32 + k] = outv;
                }
            }
            bd = converged ? p1last : prevU;   // true row r0+63 either way
        }
        if (wv < 3) {
            prevLds[wv + 1][k] = bd;
            asm volatile("s_waitcnt lgkmcnt(0)" ::: "memory");
            if (lane == 0) *((volatile unsigned int*)&locTok) = (unsigned int)(wv + 1);
        } else if ((int)blockIdx.x < WB - 1) {
            __hip_atomic_store(&gPrev[k], bd, __ATOMIC_RELAXED,
                               __HIP_MEMORY_SCOPE_AGENT);
            if (lane == 0)
                __hip_atomic_store(gTok, (unsigned int)blockIdx.x + 1u,
                                   __ATOMIC_RELEASE, __HIP_MEMORY_SCOPE_AGENT);
        }
    }

    __builtin_amdgcn_fence(__ATOMIC_RELEASE, "agent");
    cg::this_grid().sync();
    __builtin_amdgcn_fence(__ATOMIC_ACQUIRE, "agent");

    // ---------------- phase 3: unpack bits -> float, 8 px/thread ------------
    {
        const int t2 = (int)blockIdx.x * 256 + tid;   // 0..131071
        const unsigned int w = Osp[t2 >> 2];
        const int sh = (t2 & 3) << 3;
        const unsigned int b = (w >> sh) & 0xFFu;
        float4 v0, v1;
        v0.x = (b & 1u)   ? 1.f : 0.f;
        v0.y = (b & 2u)   ? 1.f : 0.f;
        v0.z = (b & 4u)   ? 1.f : 0.f;
        v0.w = (b & 8u)   ? 1.f : 0.f;
        v1.x = (b & 16u)  ? 1.f : 0.f;
        v1.y = (b & 32u)  ? 1.f : 0.f;
        v1.z = (b & 64u)  ? 1.f : 0.f;
        v1.w = (b & 128u) ? 1.f : 0.f;
        float4* o = (float4*)(out + ((long)t2 << 3));
        o[0] = v0; o[1] = v1;
    }
}

// =====================================================================
// Legacy 4-kernel path (verified @96.5us) — fallback if cooperative
// launch is rejected (e.g. under graph capture on an older runtime).
// =====================================================================
__global__ __launch_bounds__(256) void k_fused(const float* __restrict__ x,
                                               unsigned long long* __restrict__ Sp,
                                               unsigned long long* __restrict__ Wp) {
    __shared__ float g[20][72];
    __shared__ float m[18][68];
    const int bx = blockIdx.x & 15, by = blockIdx.x >> 4;
    const int tid = threadIdx.x;
    const int gi0 = by * 16 - 2, gj0 = bx * 64 - 2;

    for (int e = tid; e < 20 * 68; e += 256) {
        int ly = e / 68, lx = e - ly * 68;
        int gy = gi0 + ly, gxc = gj0 + lx;
        float v = 0.f;
        if ((unsigned)gy < (unsigned)IH && (unsigned)gxc < (unsigned)IW) {
            int p = gy * IW + gxc;
            float r = x[p], gg = x[NPIX + p], b = x[2 * NPIX + p];
            v = __fadd_rn(__fadd_rn(__fmul_rn(r, 0.2989f), __fmul_rn(gg, 0.587f)),
                          __fmul_rn(b, 0.114f));
        }
        g[ly][lx] = v;
    }
    __syncthreads();

    for (int e = tid; e < 18 * 66; e += 256) {
        int ly = e / 66, lx = e - ly * 66;
        float a00 = g[ly][lx],   a01 = g[ly][lx+1],   a02 = g[ly][lx+2];
        float a10 = g[ly+1][lx],                      a12 = g[ly+1][lx+2];
        float a20 = g[ly+2][lx], a21 = g[ly+2][lx+1], a22 = g[ly+2][lx+2];
        float gx = __fmul_rn(-1.f, a00);
        gx = __fadd_rn(gx, a02);
        gx = __fadd_rn(gx, __fmul_rn(-2.f, a10));
        gx = __fadd_rn(gx, __fmul_rn(2.f, a12));
        gx = __fadd_rn(gx, __fmul_rn(-1.f, a20));
        gx = __fadd_rn(gx, a22);
        float gy = a00;
        gy = __fadd_rn(gy, __fmul_rn(2.f, a01));
        gy = __fadd_rn(gy, a02);
        gy = __fadd_rn(gy, __fmul_rn(-1.f, a20));
        gy = __fadd_rn(gy, __fmul_rn(-2.f, a21));
        gy = __fadd_rn(gy, __fmul_rn(-1.f, a22));
        m[ly][lx] = __fsqrt_rn(__fadd_rn(__fmul_rn(gx, gx), __fmul_rn(gy, gy)));
    }
    __syncthreads();

    const int lane = tid & 63;
    const int wv = tid >> 6;
    #pragma unroll
    for (int rr = 0; rr < 4; ++rr) {
        int ti = wv * 4 + rr;
        int i = by * 16 + ti, j = bx * 64 + lane;
        float a00 = g[ti+1][lane+1], a01 = g[ti+1][lane+2], a02 = g[ti+1][lane+3];
        float a10 = g[ti+2][lane+1],                         a12 = g[ti+2][lane+3];
        float a20 = g[ti+3][lane+1], a21 = g[ti+3][lane+2], a22 = g[ti+3][lane+3];
        float gx = __fmul_rn(-1.f, a00);
        gx = __fadd_rn(gx, a02);
        gx = __fadd_rn(gx, __fmul_rn(-2.f, a10));
        gx = __fadd_rn(gx, __fmul_rn(2.f, a12));
        gx = __fadd_rn(gx, __fmul_rn(-1.f, a20));
        gx = __fadd_rn(gx, a22);
        float gy = a00;
        gy = __fadd_rn(gy, __fmul_rn(2.f, a01));
        gy = __fadd_rn(gy, a02);
        gy = __fadd_rn(gy, __fmul_rn(-1.f, a20));
        gy = __fadd_rn(gy, __fmul_rn(-2.f, a21));
        gy = __fadd_rn(gy, __fmul_rn(-1.f, a22));

        float ai = __fmul_rn(atan2f(gy, gx), 57.295779513082320876798154814105f);
        float c = m[ti+1][lane+1];
        float n1, n2;
        if (ai < -22.5f || ai >= 157.5f)      { n1 = m[ti+1][lane];   n2 = m[ti+1][lane+2]; }
        else if (ai < 22.5f)                  { n1 = m[ti][lane+1];   n2 = m[ti+2][lane+1]; }
        else if (ai < 67.5f)                  { n1 = m[ti][lane];     n2 = m[ti+2][lane+2]; }
        else if (ai < 112.5f)                 { n1 = m[ti][lane+1];   n2 = m[ti+2][lane+1]; }
        else                                  { n1 = m[ti][lane+2];   n2 = m[ti+2][lane];   }
        bool border = (i == 0) | (i == IH - 1) | (j == 0) | (j == IW - 1);
        bool keep = (c >= n1) && (c >= n2);
        float supp = keep ? c : 0.f;
        bool sb = !border && (supp >= 50.f);
        bool wb = !border && (supp >= 20.f) && !(supp >= 50.f);
        unsigned long long bs = __ballot(sb);
        unsigned long long bw = __ballot(wb);
        if (lane == 0) {
            Sp[i * 16 + bx] = bs;
            Wp[i * 16 + bx] = bw;
        }
    }
}

__global__ __launch_bounds__(64, 1) void k_spec(const unsigned int* __restrict__ Sp,
                                                const unsigned int* __restrict__ Wp,
                                                unsigned int* __restrict__ Osp) {
    __shared__ unsigned int ringW[1][8][32];
    __shared__ unsigned int ringS[1][8][32];
    const int wv = 0;
    const int c = blockIdx.x;
    const int lane = threadIdx.x;
    const int k = lane & 31;
    const int r0 = c * CH + 1;

    #pragma unroll
    for (int g = 0; g < 3; ++g) {
        dma4(Wp + (r0 + 2 * g) * 32 + lane, &ringW[0][(2 * g) & 7][0]);
        dma4(Sp + (r0 + 2 * g) * 32 + lane, &ringS[0][(2 * g) & 7][0]);
    }
    unsigned int prevU = Sp[(r0 - 1) * 32 + k];
    int tl = r0 + 64; if (tl > 1023) tl = 1023;
    unsigned int Stail = Sp[tl * 32 + k];
    unsigned int crp;
    {
        unsigned long long mh = __ballot((prevU >> 31) != 0u);
        unsigned long long ml = __ballot((prevU & 1u) != 0u);
        crp = ((((unsigned int)(mh << 1)) >> k) & 1u)
            | (((((unsigned int)(ml >> 1)) >> k) & 1u) << 31);
    }
    if (c == 0 && lane < 32) Osp[k] = 0u;
    if (c == NW - 1 && lane < 32) Osp[1023 * 32 + k] = 0u;

    asm volatile("s_waitcnt vmcnt(4)" ::: "memory");
    unsigned int SA = ringS[0][0][k];
    unsigned long long mloA = __ballot((SA & 1u) != 0u);

    #pragma unroll 1
    for (int t = 0; t < 32; ++t) {
        if (t < 29) {
            int g2 = t + 3;
            dma4(Wp + (r0 + 2 * g2) * 32 + lane, &ringW[0][(2 * g2) & 7][0]);
            dma4(Sp + (r0 + 2 * g2) * 32 + lane, &ringS[0][(2 * g2) & 7][0]);
            asm volatile("s_waitcnt vmcnt(4)" ::: "memory");
        } else if (t == 29) {
            asm volatile("s_waitcnt vmcnt(2)" ::: "memory");
        } else {
            asm volatile("s_waitcnt vmcnt(0)" ::: "memory");
        }
        SPEC_ROW(2 * t)
        SPEC_ROW(2 * t + 1)
    }
}

__global__ __launch_bounds__(1024) void k_fix(const unsigned int* __restrict__ Sp,
                                              const unsigned int* __restrict__ Wp,
                                              unsigned int* __restrict__ Osp) {
    __shared__ unsigned int prevRowLds[NW][32];
    __shared__ unsigned int fixedUpTo;
    const int tid = threadIdx.x;
    const int c = tid >> 6;
    const int lane = tid & 63;
    const int k = lane & 31;
    const int r0 = c * CH + 1;

    if (tid == 0) fixedUpTo = 0u;
    __syncthreads();

    const unsigned int* Sb = Sp + r0 * 32 + k;
    unsigned int S0 = Sb[0],   S1 = Sb[32],  S2 = Sb[64],  S3 = Sb[96],
                 S4 = Sb[128], S5 = Sb[160], S6 = Sb[192], S7 = Sb[224],
                 S8 = Sb[256];
    const unsigned int* Wb = Wp + r0 * 32 + k;
    unsigned int W0 = Wb[0],   W1 = Wb[32],  W2 = Wb[64],  W3 = Wb[96],
                 W4 = Wb[128], W5 = Wb[160], W6 = Wb[192], W7 = Wb[224];
    const unsigned int* Ob = Osp + r0 * 32 + k;
    unsigned int p0 = Ob[0],   p1 = Ob[32],  p2 = Ob[64],  p3 = Ob[96],
                 p4 = Ob[128], p5 = Ob[160], p6 = Ob[192], p7 = Ob[224];
    int lr = r0 + 63; if (lr > 1022) lr = 1022;
    unsigned int p1last = Osp[lr * 32 + k];
    unsigned int T0, T1, T2, T3, T4, T5, T6, T7;
    MKT(T0, S0, S1) MKT(T1, S1, S2) MKT(T2, S2, S3) MKT(T3, S3, S4)
    MKT(T4, S4, S5) MKT(T5, S5, S6) MKT(T6, S6, S7) MKT(T7, S7, S8)

    unsigned int bd = p1last;
    bool done = false, converged = false;
    unsigned int prevU = 0u, crp = 0u;
    if (c > 0) {
        while (*((volatile unsigned int*)&fixedUpTo) != (unsigned int)c)
            __builtin_amdgcn_s_sleep(1);
        asm volatile("" ::: "memory");
        prevU = prevRowLds[c][k];
        {
            unsigned long long mh = __ballot((prevU >> 31) != 0u);
            unsigned long long ml = __ballot((prevU & 1u) != 0u);
            crp = ((((unsigned int)(mh << 1)) >> k) & 1u)
                | (((((unsigned int)(ml >> 1)) >> k) & 1u) << 31);
        }
        FIX_STEP(0, W0, S0, T0, p0) FIX_STEP(1, W1, S1, T1, p1)
        FIX_STEP(2, W2, S2, T2, p2) FIX_STEP(3, W3, S3, T3, p3)
        FIX_STEP(4, W4, S4, T4, p4) FIX_STEP(5, W5, S5, T5, p5)
        FIX_STEP(6, W6, S6, T6, p6) FIX_STEP(7, W7, S7, T7, p7)
        if (!done) {
            #pragma unroll 1
            for (int d = 8; d < CH; ++d) {
                int r = r0 + d;
                if (r > 1022) break;
                unsigned int Wv = Wp[r * 32 + k];
                unsigned int Sv = Sp[r * 32 + k];
                int rn = r + 1; if (rn > 1023) rn = 1023;
                unsigned int Sn = Sp[rn * 32 + k];
                unsigned int sp = Osp[r * 32 + k];
                unsigned int Tv;
                MKT(Tv, Sv, Sn)
                CHAIN_STEP(Wv, Sv, Tv)
                unsigned long long df = __ballot(outv != sp);
                if ((df & 0xFFFFFFFFull) == 0ull) { converged = true; break; }
                Osp[r * 32 + k] = outv;
            }
        }
        bd = converged ? p1last : prevU;
    }
    if (c < NW - 1) prevRowLds[c + 1][k] = bd;
    asm volatile("s_waitcnt lgkmcnt(0)" ::: "memory");
    if (lane == 0) *((volatile unsigned int*)&fixedUpTo) = (unsigned int)(c + 1);
}

__global__ __launch_bounds__(256) void k_unpack(const unsigned int* __restrict__ Osp,
                                                float* __restrict__ out) {
    int t = blockIdx.x * blockDim.x + threadIdx.x;
    int px = t * 4;
    if (px >= NPIX) return;
    unsigned int w = Osp[px >> 5];
    int sh = px & 31;
    float4 v;
    v.x = ((w >> (sh + 0)) & 1u) ? 1.f : 0.f;
    v.y = ((w >> (sh + 1)) & 1u) ? 1.f : 0.f;
    v.z = ((w >> (sh + 2)) & 1u) ? 1.f : 0.f;
    v.w = ((w >> (sh + 3)) & 1u) ? 1.f : 0.f;
    *((float4*)(out + px)) = v;
}

extern "C" void kernel_launch(void* const* d_in, const int* in_sizes, int n_in,
                              void* d_out, int out_size, void* d_ws, size_t ws_size,
                              hipStream_t stream) {
    const float* x = (const float*)d_in[0];
    float* out = (float*)d_out;
    char* ws = (char*)d_ws;

    unsigned long long* Sp = (unsigned long long*)(ws);
    unsigned long long* Wp = (unsigned long long*)(ws + 128u * 1024u);
    unsigned int*      Osp = (unsigned int*)(ws + 256u * 1024u);
    unsigned int*      gTok = (unsigned int*)(ws + 384u * 1024u);
    unsigned int*      gPrev = (unsigned int*)(ws + 384u * 1024u + 256u);
    // gTok starts 0xAAAAAAAA (ws poison) != any token value 1..3 -> no init
    // needed; protocol writes it in order each launch.

    void* args[7];
    args[0] = (void*)&x;
    args[1] = (void*)&Sp;
    args[2] = (void*)&Wp;
    args[3] = (void*)&Osp;
    args[4] = (void*)&out;
    args[5] = (void*)&gTok;
    args[6] = (void*)&gPrev;
    hipError_t err = hipLaunchCooperativeKernel((const void*)k_canny,
                                                dim3(512), dim3(256),
                                                args, 0, stream);
    if (err != hipSuccess) {
        (void)hipGetLastError();   // clear error state, take legacy path
        k_fused<<<1024, 256, 0, stream>>>(x, Sp, Wp);
        k_spec<<<NW, 64, 0, stream>>>((const unsigned int*)Sp,
                                      (const unsigned int*)Wp, Osp);
        k_fix<<<1, 1024, 0, stream>>>((const unsigned int*)Sp,
                                      (const unsigned int*)Wp, Osp);
        k_unpack<<<1024, 256, 0, stream>>>((const unsigned int*)Osp, out);
    }
}

// Round 2
// 104.510 us; speedup vs baseline: 2.7754x; 2.7754x over previous
//
#include <hip/hip_runtime.h>
#include <math.h>

#define IH 1024
#define IW 1024
#define NPIX (IH * IW)
#define NW 16   // chunks
#define CH 64   // rows per chunk

// async global->LDS: 64 lanes x 4B = 256 B = TWO consecutive 32-word rows
__device__ __forceinline__ void dma4(const unsigned int* g, unsigned int* l) {
    __builtin_amdgcn_global_load_lds(
        (const __attribute__((address_space(1))) void*)g,
        (__attribute__((address_space(3))) void*)l, 4, 0, 0);
}

// One row of the recurrence (verified absmax 0 since R8).
#define CHAIN_STEP(W_, S_, T_)                                                  \
    unsigned int hxp = (prevU << 1) | prevU | ((prevU >> 1) | crp);             \
    unsigned int seed = hxp | (T_);                                             \
    unsigned int P = (W_);                                                      \
    unsigned int G = (S_) | (P & seed);                                         \
    unsigned int A = G | P;                                                     \
    unsigned int AXG = A ^ G;                                                   \
    unsigned int s1v = A + G;                                                   \
    unsigned long long gm = __ballot(s1v < A) & 0xFFFFFFFFull;                  \
    unsigned long long pm = __ballot(s1v == 0xFFFFFFFFu) & 0xFFFFFFFFull;       \
    unsigned long long G0 = __ballot((G & 1u) != 0u);                           \
    unsigned long long P0 = __ballot((P & 1u) != 0u);                           \
    unsigned long long aa = gm | pm;                                            \
    unsigned long long ssum = aa + gm;                                          \
    unsigned long long cvw = ssum ^ aa ^ gm;                                    \
    unsigned long long mlo_o = G0 | (P0 & cvw);                                 \
    unsigned int cin = (((unsigned int)cvw) >> k) & 1u;                         \
    unsigned int ovb = ((((unsigned int)(cvw >> 1)) >> k) & 1u) << 31;          \
    unsigned int s2 = s1v + cin;                                                \
    unsigned int outv = ((s2 ^ AXG) >> 1) | ovb;                                \
    unsigned int rtP = ((((unsigned int)(mlo_o >> 1)) >> k) & 1u) << 31;        \
    crp = cin | rtP;                                                            \
    prevU = outv;

// STAT_r = Rx(S_r) | Hx(S_{r+1})  (verified)
#define MKT(T_, SA_, SN_) {                                                     \
    unsigned long long mla = __ballot(((SA_) & 1u) != 0u);                      \
    unsigned long long mln = __ballot(((SN_) & 1u) != 0u);                      \
    unsigned long long mhn = __ballot(((SN_) >> 31) != 0u);                     \
    unsigned int rxC = (SA_) | ((SA_) >> 1)                                     \
                     | (((((unsigned int)(mla >> 1)) >> k) & 1u) << 31);        \
    unsigned int hxN = (SN_) | ((SN_) << 1) | ((SN_) >> 1)                      \
                     | ((((unsigned int)(mhn << 1)) >> k) & 1u)                 \
                     | (((((unsigned int)(mln >> 1)) >> k) & 1u) << 31);        \
    T_ = rxC | hxN; }

// Spec row: bits only (R12: no float output from 16 waves). Ring indexed by wv.
#define SPEC_ROW(dd) {                                                          \
    const int d = (dd);                                                         \
    const int r = r0 + d;                                                       \
    unsigned int Wv = ringW[wv][d & 7][k];                                      \
    unsigned int RS = (d < 63) ? ringS[wv][(d + 1) & 7][k] : Stail;             \
    unsigned long long mhiN = __ballot((RS >> 31) != 0u);                       \
    unsigned long long mloN = __ballot((RS & 1u) != 0u);                        \
    unsigned int rxC = SA | (SA >> 1)                                           \
                     | (((((unsigned int)(mloA >> 1)) >> k) & 1u) << 31);       \
    unsigned int hxN = RS | (RS << 1) | (RS >> 1)                               \
                     | ((((unsigned int)(mhiN << 1)) >> k) & 1u)                \
                     | (((((unsigned int)(mloN >> 1)) >> k) & 1u) << 31);       \
    unsigned int Tv = rxC | hxN;                                                \
    CHAIN_STEP(Wv, SA, Tv)                                                      \
    if (r <= 1022) Osp[r * 32 + k] = outv;                                      \
    SA = RS; mloA = mloN;                                                       \
}

#define FIX_STEP(d, W_, S_, T_, SP_) if (!done) {                               \
    const int r = r0 + (d);                                                     \
    CHAIN_STEP(W_, S_, T_)                                                      \
    unsigned long long df = __ballot(outv != (SP_));                            \
    if ((df & 0xFFFFFFFFull) == 0ull) { done = true; converged = true; }        \
    else Osp[r * 32 + k] = outv;                                                \
}

// ---------------- Stage 1+2+3 fused: gray -> Sobel -> NMS -> bit-packed ----------
// (unchanged from the verified 96.5us version)
__global__ __launch_bounds__(256) void k_fused(const float* __restrict__ x,
                                               unsigned long long* __restrict__ Sp,
                                               unsigned long long* __restrict__ Wp) {
    __shared__ float g[20][72];
    __shared__ float m[18][68];
    const int bx = blockIdx.x & 15, by = blockIdx.x >> 4;
    const int tid = threadIdx.x;
    const int gi0 = by * 16 - 2, gj0 = bx * 64 - 2;

    for (int e = tid; e < 20 * 68; e += 256) {
        int ly = e / 68, lx = e - ly * 68;
        int gy = gi0 + ly, gxc = gj0 + lx;
        float v = 0.f;
        if ((unsigned)gy < (unsigned)IH && (unsigned)gxc < (unsigned)IW) {
            int p = gy * IW + gxc;
            float r = x[p], gg = x[NPIX + p], b = x[2 * NPIX + p];
            v = __fadd_rn(__fadd_rn(__fmul_rn(r, 0.2989f), __fmul_rn(gg, 0.587f)),
                          __fmul_rn(b, 0.114f));
        }
        g[ly][lx] = v;
    }
    __syncthreads();

    for (int e = tid; e < 18 * 66; e += 256) {
        int ly = e / 66, lx = e - ly * 66;
        float a00 = g[ly][lx],   a01 = g[ly][lx+1],   a02 = g[ly][lx+2];
        float a10 = g[ly+1][lx],                      a12 = g[ly+1][lx+2];
        float a20 = g[ly+2][lx], a21 = g[ly+2][lx+1], a22 = g[ly+2][lx+2];
        float gx = __fmul_rn(-1.f, a00);
        gx = __fadd_rn(gx, a02);
        gx = __fadd_rn(gx, __fmul_rn(-2.f, a10));
        gx = __fadd_rn(gx, __fmul_rn(2.f, a12));
        gx = __fadd_rn(gx, __fmul_rn(-1.f, a20));
        gx = __fadd_rn(gx, a22);
        float gy = a00;
        gy = __fadd_rn(gy, __fmul_rn(2.f, a01));
        gy = __fadd_rn(gy, a02);
        gy = __fadd_rn(gy, __fmul_rn(-1.f, a20));
        gy = __fadd_rn(gy, __fmul_rn(-2.f, a21));
        gy = __fadd_rn(gy, __fmul_rn(-1.f, a22));
        m[ly][lx] = __fsqrt_rn(__fadd_rn(__fmul_rn(gx, gx), __fmul_rn(gy, gy)));
    }
    __syncthreads();

    const int lane = tid & 63;
    const int wv = tid >> 6;
    #pragma unroll
    for (int rr = 0; rr < 4; ++rr) {
        int ti = wv * 4 + rr;
        int i = by * 16 + ti, j = bx * 64 + lane;
        float a00 = g[ti+1][lane+1], a01 = g[ti+1][lane+2], a02 = g[ti+1][lane+3];
        float a10 = g[ti+2][lane+1],                         a12 = g[ti+2][lane+3];
        float a20 = g[ti+3][lane+1], a21 = g[ti+3][lane+2], a22 = g[ti+3][lane+3];
        float gx = __fmul_rn(-1.f, a00);
        gx = __fadd_rn(gx, a02);
        gx = __fadd_rn(gx, __fmul_rn(-2.f, a10));
        gx = __fadd_rn(gx, __fmul_rn(2.f, a12));
        gx = __fadd_rn(gx, __fmul_rn(-1.f, a20));
        gx = __fadd_rn(gx, a22);
        float gy = a00;
        gy = __fadd_rn(gy, __fmul_rn(2.f, a01));
        gy = __fadd_rn(gy, a02);
        gy = __fadd_rn(gy, __fmul_rn(-1.f, a20));
        gy = __fadd_rn(gy, __fmul_rn(-2.f, a21));
        gy = __fadd_rn(gy, __fmul_rn(-1.f, a22));

        float ai = __fmul_rn(atan2f(gy, gx), 57.295779513082320876798154814105f);
        float c = m[ti+1][lane+1];
        float n1, n2;
        if (ai < -22.5f || ai >= 157.5f)      { n1 = m[ti+1][lane];   n2 = m[ti+1][lane+2]; }
        else if (ai < 22.5f)                  { n1 = m[ti][lane+1];   n2 = m[ti+2][lane+1]; }
        else if (ai < 67.5f)                  { n1 = m[ti][lane];     n2 = m[ti+2][lane+2]; }
        else if (ai < 112.5f)                 { n1 = m[ti][lane+1];   n2 = m[ti+2][lane+1]; }
        else                                  { n1 = m[ti][lane+2];   n2 = m[ti+2][lane];   }
        bool border = (i == 0) | (i == IH - 1) | (j == 0) | (j == IW - 1);
        bool keep = (c >= n1) && (c >= n2);
        float supp = keep ? c : 0.f;
        bool sb = !border && (supp >= 50.f);
        bool wb = !border && (supp >= 20.f) && !(supp >= 50.f);
        unsigned long long bs = __ballot(sb);
        unsigned long long bw = __ballot(wb);
        if (lane == 0) {
            Sp[i * 16 + bx] = bs;
            Wp[i * 16 + bx] = bw;
        }
    }
}

// =====================================================================
// Stage 4+5 fused: block 0 = spec (16 waves, LDS rings) + fix (LDS token
// chain, verified k_fix pattern) publishing per-chunk done flags;
// blocks 1..64 = unpack consumers (16 rows each), spin relaxed on the
// flag then acquire-fence and unpack. Block 0 never waits on anyone ->
// deadlock-free without cooperative launch (grid 65 <= 256 CUs anyway).
// Flag: 0xC0DE0000|n means chunks 0..n-1 final. ws poison 0xAAAAAAAA
// reads as "not ready" (same precedent as the verified gTok design).
// =====================================================================
__global__ __launch_bounds__(1024) void k_specfix(const unsigned int* __restrict__ Sp,
                                                  const unsigned int* __restrict__ Wp,
                                                  unsigned int* __restrict__ Osp,
                                                  float* __restrict__ out,
                                                  unsigned int* __restrict__ gFix) {
    __shared__ unsigned int ringW[16][8][32];
    __shared__ unsigned int ringS[16][8][32];
    __shared__ unsigned int prevLds[16][32];
    __shared__ unsigned int locTok;
    const int tid = threadIdx.x;

    if (blockIdx.x != 0) {
        // ---------------- unpack consumer: 16 rows per block ----------------
        const int b = (int)blockIdx.x;                     // 1..64
        const unsigned int need = (unsigned int)(((16 * b - 2) >> 6) + 1);
        if (tid == 0) {
            for (;;) {
                unsigned int v = __hip_atomic_load(gFix, __ATOMIC_RELAXED,
                                                   __HIP_MEMORY_SCOPE_AGENT);
                if ((v & 0xFFFFFF00u) == 0xC0DE0000u && (v & 0xFFu) >= need) break;
                __builtin_amdgcn_s_sleep(8);
            }
        }
        __syncthreads();
        __builtin_amdgcn_fence(__ATOMIC_ACQUIRE, "agent");
        const int px = ((b - 1) * 1024 + tid) * 16;        // 16 px per thread
        unsigned int w = Osp[px >> 5];
        unsigned int bits = (w >> (px & 16)) & 0xFFFFu;
        float4* o = (float4*)(out + px);
        #pragma unroll
        for (int q = 0; q < 4; ++q) {
            float4 v;
            v.x = (bits & (1u << (4 * q + 0))) ? 1.f : 0.f;
            v.y = (bits & (1u << (4 * q + 1))) ? 1.f : 0.f;
            v.z = (bits & (1u << (4 * q + 2))) ? 1.f : 0.f;
            v.w = (bits & (1u << (4 * q + 3))) ? 1.f : 0.f;
            o[q] = v;
        }
        return;
    }

    // ---------------- block 0: spec + fix, 16 chunk-waves --------------------
    const int wv = tid >> 6;          // chunk 0..15
    const int lane = tid & 63;
    const int k = lane & 31;
    const int c = wv;
    const int r0 = c * CH + 1;

    if (tid == 0) locTok = 0u;
    __syncthreads();

    // --- spec (verified ring + counted-vmcnt structure, ring per wave) ---
    #pragma unroll
    for (int gq = 0; gq < 3; ++gq) {
        dma4(Wp + (r0 + 2 * gq) * 32 + lane, &ringW[wv][(2 * gq) & 7][0]);
        dma4(Sp + (r0 + 2 * gq) * 32 + lane, &ringS[wv][(2 * gq) & 7][0]);
    }
    unsigned int prevU = Sp[(r0 - 1) * 32 + k];   // static lower bound
    int tl = r0 + 64; if (tl > 1023) tl = 1023;
    unsigned int Stail = Sp[tl * 32 + k];
    unsigned int crp;
    {
        unsigned long long mh = __ballot((prevU >> 31) != 0u);
        unsigned long long ml = __ballot((prevU & 1u) != 0u);
        crp = ((((unsigned int)(mh << 1)) >> k) & 1u)
            | (((((unsigned int)(ml >> 1)) >> k) & 1u) << 31);
    }
    if (c == 0 && lane < 32) Osp[k] = 0u;
    if (c == NW - 1 && lane < 32) Osp[1023 * 32 + k] = 0u;

    asm volatile("s_waitcnt vmcnt(4)" ::: "memory");
    unsigned int SA = ringS[wv][0][k];
    unsigned long long mloA = __ballot((SA & 1u) != 0u);

    #pragma unroll 1
    for (int t = 0; t < 32; ++t) {
        if (t < 29) {
            int g2 = t + 3;
            dma4(Wp + (r0 + 2 * g2) * 32 + lane, &ringW[wv][(2 * g2) & 7][0]);
            dma4(Sp + (r0 + 2 * g2) * 32 + lane, &ringS[wv][(2 * g2) & 7][0]);
            asm volatile("s_waitcnt vmcnt(4)" ::: "memory");
        } else if (t == 29) {
            asm volatile("s_waitcnt vmcnt(2)" ::: "memory");
        } else {
            asm volatile("s_waitcnt vmcnt(0)" ::: "memory");
        }
        SPEC_ROW(2 * t)
        SPEC_ROW(2 * t + 1)
    }
    // drain spec stores before re-reading Osp (same-wave st->ld) and flagging
    asm volatile("s_waitcnt vmcnt(0)" ::: "memory");

    // --- prestage fix state (L2-hot from spec's own streaming) ---
    const unsigned int* Sb = Sp + r0 * 32 + k;
    unsigned int S0 = Sb[0],   S1 = Sb[32],  S2 = Sb[64],  S3 = Sb[96],
                 S4 = Sb[128], S5 = Sb[160], S6 = Sb[192], S7 = Sb[224],
                 S8 = Sb[256];
    const unsigned int* Wb = Wp + r0 * 32 + k;
    unsigned int W0 = Wb[0],   W1 = Wb[32],  W2 = Wb[64],  W3 = Wb[96],
                 W4 = Wb[128], W5 = Wb[160], W6 = Wb[192], W7 = Wb[224];
    const unsigned int* Ob = Osp + r0 * 32 + k;
    unsigned int p0 = Ob[0],   p1 = Ob[32],  p2 = Ob[64],  p3 = Ob[96],
                 p4 = Ob[128], p5 = Ob[160], p6 = Ob[192], p7 = Ob[224];
    int lr = r0 + 63; if (lr > 1022) lr = 1022;
    unsigned int p1last = Osp[lr * 32 + k];
    unsigned int T0, T1, T2, T3, T4, T5, T6, T7;
    MKT(T0, S0, S1) MKT(T1, S1, S2) MKT(T2, S2, S3) MKT(T3, S3, S4)
    MKT(T4, S4, S5) MKT(T5, S5, S6) MKT(T6, S6, S7) MKT(T7, S7, S8)

    unsigned int bd = p1last;
    bool done = false, converged = false;
    prevU = 0u; crp = 0u;
    if (c > 0) {
        while (*((volatile unsigned int*)&locTok) != (unsigned int)c)
            __builtin_amdgcn_s_sleep(1);
        asm volatile("" ::: "memory");
        prevU = prevLds[c][k];            // true last row of chunk c-1
        {
            unsigned long long mh = __ballot((prevU >> 31) != 0u);
            unsigned long long ml = __ballot((prevU & 1u) != 0u);
            crp = ((((unsigned int)(mh << 1)) >> k) & 1u)
                | (((((unsigned int)(ml >> 1)) >> k) & 1u) << 31);
        }
        FIX_STEP(0, W0, S0, T0, p0) FIX_STEP(1, W1, S1, T1, p1)
        FIX_STEP(2, W2, S2, T2, p2) FIX_STEP(3, W3, S3, T3, p3)
        FIX_STEP(4, W4, S4, T4, p4) FIX_STEP(5, W5, S5, T5, p5)
        FIX_STEP(6, W6, S6, T6, p6) FIX_STEP(7, W7, S7, T7, p7)
        if (!done) {
            #pragma unroll 1
            for (int d = 8; d < CH; ++d) {     // rare deep path: global loads
                int r = r0 + d;
                if (r > 1022) break;
                unsigned int Wv = Wp[r * 32 + k];
                unsigned int Sv = Sp[r * 32 + k];
                int rn = r + 1; if (rn > 1023) rn = 1023;
                unsigned int Sn = Sp[rn * 32 + k];
                unsigned int sp = Osp[r * 32 + k];
                unsigned int Tv;
                MKT(Tv, Sv, Sn)
                CHAIN_STEP(Wv, Sv, Tv)
                unsigned long long df = __ballot(outv != sp);
                if ((df & 0xFFFFFFFFull) == 0ull) { converged = true; break; }
                Osp[r * 32 + k] = outv;
            }
        }
        bd = converged ? p1last : prevU;     // true row r0+63 either way
    }
    // pass token to next chunk-wave first (critical chain), then publish flag
    if (c < NW - 1) prevLds[c + 1][k] = bd;
    asm volatile("s_waitcnt lgkmcnt(0)" ::: "memory");
    if (lane == 0) *((volatile unsigned int*)&locTok) = (unsigned int)(c + 1);
    if (lane == 0)
        (void)__hip_atomic_fetch_max(gFix, 0xC0DE0000u | (unsigned int)(c + 1),
                                     __ATOMIC_RELEASE, __HIP_MEMORY_SCOPE_AGENT);
}

extern "C" void kernel_launch(void* const* d_in, const int* in_sizes, int n_in,
                              void* d_out, int out_size, void* d_ws, size_t ws_size,
                              hipStream_t stream) {
    const float* x = (const float*)d_in[0];
    float* out = (float*)d_out;
    char* ws = (char*)d_ws;

    unsigned long long* Sp = (unsigned long long*)(ws);
    unsigned long long* Wp = (unsigned long long*)(ws + 128u * 1024u);
    unsigned int*      Osp = (unsigned int*)(ws + 256u * 1024u);
    unsigned int*      gFix = (unsigned int*)(ws + 384u * 1024u);
    // gFix starts 0xAAAAAAAA (ws poison) -> "not ready"; block 0 publishes
    // 0xC0DE0000|n monotonically via fetch_max each launch.

    k_fused<<<1024, 256, 0, stream>>>(x, Sp, Wp);
    k_specfix<<<65, 1024, 0, stream>>>((const unsigned int*)Sp,
                                       (const unsigned int*)Wp,
                                       Osp, out, gFix);
}

// Round 3
// 103.722 us; speedup vs baseline: 2.7964x; 1.0076x over previous
//
#include <hip/hip_runtime.h>
#include <math.h>

#define IH 1024
#define IW 1024
#define NPIX (IH * IW)
#define NW 16   // chunks
#define CH 64   // rows per chunk

#define SPEC_DONE 0x5EC0DE01u
#define FIX_DONE  0xF1DE0001u
#define FLAG_STRIDE 64   // uints = 256 B between flag lines

// async global->LDS: 64 lanes x 4B = 256 B = TWO consecutive 32-word rows
__device__ __forceinline__ void dma4(const unsigned int* g, unsigned int* l) {
    __builtin_amdgcn_global_load_lds(
        (const __attribute__((address_space(1))) void*)g,
        (__attribute__((address_space(3))) void*)l, 4, 0, 0);
}

// One row of the recurrence (verified absmax 0 since R8).
#define CHAIN_STEP(W_, S_, T_)                                                  \
    unsigned int hxp = (prevU << 1) | prevU | ((prevU >> 1) | crp);             \
    unsigned int seed = hxp | (T_);                                             \
    unsigned int P = (W_);                                                      \
    unsigned int G = (S_) | (P & seed);                                         \
    unsigned int A = G | P;                                                     \
    unsigned int AXG = A ^ G;                                                   \
    unsigned int s1v = A + G;                                                   \
    unsigned long long gm = __ballot(s1v < A) & 0xFFFFFFFFull;                  \
    unsigned long long pm = __ballot(s1v == 0xFFFFFFFFu) & 0xFFFFFFFFull;       \
    unsigned long long G0 = __ballot((G & 1u) != 0u);                           \
    unsigned long long P0 = __ballot((P & 1u) != 0u);                           \
    unsigned long long aa = gm | pm;                                            \
    unsigned long long ssum = aa + gm;                                          \
    unsigned long long cvw = ssum ^ aa ^ gm;                                    \
    unsigned long long mlo_o = G0 | (P0 & cvw);                                 \
    unsigned int cin = (((unsigned int)cvw) >> k) & 1u;                         \
    unsigned int ovb = ((((unsigned int)(cvw >> 1)) >> k) & 1u) << 31;          \
    unsigned int s2 = s1v + cin;                                                \
    unsigned int outv = ((s2 ^ AXG) >> 1) | ovb;                                \
    unsigned int rtP = ((((unsigned int)(mlo_o >> 1)) >> k) & 1u) << 31;        \
    crp = cin | rtP;                                                            \
    prevU = outv;

// STAT_r = Rx(S_r) | Hx(S_{r+1})  (verified)
#define MKT(T_, SA_, SN_) {                                                     \
    unsigned long long mla = __ballot(((SA_) & 1u) != 0u);                      \
    unsigned long long mln = __ballot(((SN_) & 1u) != 0u);                      \
    unsigned long long mhn = __ballot(((SN_) >> 31) != 0u);                     \
    unsigned int rxC = (SA_) | ((SA_) >> 1)                                     \
                     | (((((unsigned int)(mla >> 1)) >> k) & 1u) << 31);        \
    unsigned int hxN = (SN_) | ((SN_) << 1) | ((SN_) >> 1)                      \
                     | ((((unsigned int)(mhn << 1)) >> k) & 1u)                 \
                     | (((((unsigned int)(mln >> 1)) >> k) & 1u) << 31);        \
    T_ = rxC | hxN; }

// Spec row: bits only (R12: no float output from 16 waves).
#define SPEC_ROW(dd) {                                                          \
    const int d = (dd);                                                         \
    const int r = r0 + d;                                                       \
    unsigned int Wv = ringW[d & 7][k];                                          \
    unsigned int RS = (d < 63) ? ringS[(d + 1) & 7][k] : Stail;                 \
    unsigned long long mhiN = __ballot((RS >> 31) != 0u);                       \
    unsigned long long mloN = __ballot((RS & 1u) != 0u);                        \
    unsigned int rxC = SA | (SA >> 1)                                           \
                     | (((((unsigned int)(mloA >> 1)) >> k) & 1u) << 31);       \
    unsigned int hxN = RS | (RS << 1) | (RS >> 1)                               \
                     | ((((unsigned int)(mhiN << 1)) >> k) & 1u)                \
                     | (((((unsigned int)(mloN >> 1)) >> k) & 1u) << 31);       \
    unsigned int Tv = rxC | hxN;                                                \
    CHAIN_STEP(Wv, SA, Tv)                                                      \
    if (r <= 1022) Osp[r * 32 + k] = outv;                                      \
    SA = RS; mloA = mloN;                                                       \
}

// Full spec for chunk c_ (verified legacy k_spec structure). Leaves the final
// row value (row r0+63) in BD_. Uses in-scope ringW/ringS/Osp/lane/k.
#define SPEC_CHUNK(c_, BD_) {                                                   \
    const int c = (c_);                                                         \
    const int r0 = c * CH + 1;                                                  \
    _Pragma("unroll")                                                           \
    for (int gq = 0; gq < 3; ++gq) {                                            \
        dma4(Wp + (r0 + 2 * gq) * 32 + lane, &ringW[(2 * gq) & 7][0]);          \
        dma4(Sp + (r0 + 2 * gq) * 32 + lane, &ringS[(2 * gq) & 7][0]);          \
    }                                                                           \
    unsigned int prevU = Sp[(r0 - 1) * 32 + k];                                 \
    int tl = r0 + 64; if (tl > 1023) tl = 1023;                                 \
    unsigned int Stail = Sp[tl * 32 + k];                                       \
    unsigned int crp;                                                           \
    {                                                                           \
        unsigned long long mh = __ballot((prevU >> 31) != 0u);                  \
        unsigned long long ml = __ballot((prevU & 1u) != 0u);                   \
        crp = ((((unsigned int)(mh << 1)) >> k) & 1u)                           \
            | (((((unsigned int)(ml >> 1)) >> k) & 1u) << 31);                  \
    }                                                                           \
    if (c == 0 && lane < 32) Osp[k] = 0u;                                       \
    if (c == NW - 1 && lane < 32) Osp[1023 * 32 + k] = 0u;                      \
    asm volatile("s_waitcnt vmcnt(4)" ::: "memory");                            \
    unsigned int SA = ringS[0][k];                                              \
    unsigned long long mloA = __ballot((SA & 1u) != 0u);                        \
    _Pragma("unroll 1")                                                         \
    for (int t = 0; t < 32; ++t) {                                              \
        if (t < 29) {                                                           \
            int g2 = t + 3;                                                     \
            dma4(Wp + (r0 + 2 * g2) * 32 + lane, &ringW[(2 * g2) & 7][0]);      \
            dma4(Sp + (r0 + 2 * g2) * 32 + lane, &ringS[(2 * g2) & 7][0]);      \
            asm volatile("s_waitcnt vmcnt(4)" ::: "memory");                    \
        } else if (t == 29) {                                                   \
            asm volatile("s_waitcnt vmcnt(2)" ::: "memory");                    \
        } else {                                                                \
            asm volatile("s_waitcnt vmcnt(0)" ::: "memory");                    \
        }                                                                       \
        SPEC_ROW(2 * t)                                                         \
        SPEC_ROW(2 * t + 1)                                                     \
    }                                                                           \
    asm volatile("s_waitcnt vmcnt(0)" ::: "memory");                            \
    BD_ = prevU;                                                                \
}

#define FIX_STEP(d, W_, S_, T_, SP_) if (!done) {                               \
    const int r = r0 + (d);                                                     \
    CHAIN_STEP(W_, S_, T_)                                                      \
    unsigned long long df = __ballot(outv != (SP_));                            \
    if ((df & 0xFFFFFFFFull) == 0ull) { done = true; converged = true; }        \
    else Osp[r * 32 + k] = outv;                                                \
}

// ---------------- Stage 1+2+3 fused: gray -> Sobel -> NMS -> bit-packed ------
// (unchanged from the verified 96.5us version)
__global__ __launch_bounds__(256) void k_fused(const float* __restrict__ x,
                                               unsigned long long* __restrict__ Sp,
                                               unsigned long long* __restrict__ Wp) {
    __shared__ float g[20][72];
    __shared__ float m[18][68];
    const int bx = blockIdx.x & 15, by = blockIdx.x >> 4;
    const int tid = threadIdx.x;
    const int gi0 = by * 16 - 2, gj0 = bx * 64 - 2;

    for (int e = tid; e < 20 * 68; e += 256) {
        int ly = e / 68, lx = e - ly * 68;
        int gy = gi0 + ly, gxc = gj0 + lx;
        float v = 0.f;
        if ((unsigned)gy < (unsigned)IH && (unsigned)gxc < (unsigned)IW) {
            int p = gy * IW + gxc;
            float r = x[p], gg = x[NPIX + p], b = x[2 * NPIX + p];
            v = __fadd_rn(__fadd_rn(__fmul_rn(r, 0.2989f), __fmul_rn(gg, 0.587f)),
                          __fmul_rn(b, 0.114f));
        }
        g[ly][lx] = v;
    }
    __syncthreads();

    for (int e = tid; e < 18 * 66; e += 256) {
        int ly = e / 66, lx = e - ly * 66;
        float a00 = g[ly][lx],   a01 = g[ly][lx+1],   a02 = g[ly][lx+2];
        float a10 = g[ly+1][lx],                      a12 = g[ly+1][lx+2];
        float a20 = g[ly+2][lx], a21 = g[ly+2][lx+1], a22 = g[ly+2][lx+2];
        float gx = __fmul_rn(-1.f, a00);
        gx = __fadd_rn(gx, a02);
        gx = __fadd_rn(gx, __fmul_rn(-2.f, a10));
        gx = __fadd_rn(gx, __fmul_rn(2.f, a12));
        gx = __fadd_rn(gx, __fmul_rn(-1.f, a20));
        gx = __fadd_rn(gx, a22);
        float gy = a00;
        gy = __fadd_rn(gy, __fmul_rn(2.f, a01));
        gy = __fadd_rn(gy, a02);
        gy = __fadd_rn(gy, __fmul_rn(-1.f, a20));
        gy = __fadd_rn(gy, __fmul_rn(-2.f, a21));
        gy = __fadd_rn(gy, __fmul_rn(-1.f, a22));
        m[ly][lx] = __fsqrt_rn(__fadd_rn(__fmul_rn(gx, gx), __fmul_rn(gy, gy)));
    }
    __syncthreads();

    const int lane = tid & 63;
    const int wv = tid >> 6;
    #pragma unroll
    for (int rr = 0; rr < 4; ++rr) {
        int ti = wv * 4 + rr;
        int i = by * 16 + ti, j = bx * 64 + lane;
        float a00 = g[ti+1][lane+1], a01 = g[ti+1][lane+2], a02 = g[ti+1][lane+3];
        float a10 = g[ti+2][lane+1],                         a12 = g[ti+2][lane+3];
        float a20 = g[ti+3][lane+1], a21 = g[ti+3][lane+2], a22 = g[ti+3][lane+3];
        float gx = __fmul_rn(-1.f, a00);
        gx = __fadd_rn(gx, a02);
        gx = __fadd_rn(gx, __fmul_rn(-2.f, a10));
        gx = __fadd_rn(gx, __fmul_rn(2.f, a12));
        gx = __fadd_rn(gx, __fmul_rn(-1.f, a20));
        gx = __fadd_rn(gx, a22);
        float gy = a00;
        gy = __fadd_rn(gy, __fmul_rn(2.f, a01));
        gy = __fadd_rn(gy, a02);
        gy = __fadd_rn(gy, __fmul_rn(-1.f, a20));
        gy = __fadd_rn(gy, __fmul_rn(-2.f, a21));
        gy = __fadd_rn(gy, __fmul_rn(-1.f, a22));

        float ai = __fmul_rn(atan2f(gy, gx), 57.295779513082320876798154814105f);
        float c = m[ti+1][lane+1];
        float n1, n2;
        if (ai < -22.5f || ai >= 157.5f)      { n1 = m[ti+1][lane];   n2 = m[ti+1][lane+2]; }
        else if (ai < 22.5f)                  { n1 = m[ti][lane+1];   n2 = m[ti+2][lane+1]; }
        else if (ai < 67.5f)                  { n1 = m[ti][lane];     n2 = m[ti+2][lane+2]; }
        else if (ai < 112.5f)                 { n1 = m[ti][lane+1];   n2 = m[ti+2][lane+1]; }
        else                                  { n1 = m[ti][lane+2];   n2 = m[ti+2][lane];   }
        bool border = (i == 0) | (i == IH - 1) | (j == 0) | (j == IW - 1);
        bool keep = (c >= n1) && (c >= n2);
        float supp = keep ? c : 0.f;
        bool sb = !border && (supp >= 50.f);
        bool wb = !border && (supp >= 20.f) && !(supp >= 50.f);
        unsigned long long bs = __ballot(sb);
        unsigned long long bw = __ballot(wb);
        if (lane == 0) {
            Sp[i * 16 + bx] = bs;
            Wp[i * 16 + bx] = bw;
        }
    }
}

// =====================================================================
// Stage 4+5 fused, R3 layout (fixes R2's two regressions):
//   blocks 1..15 : spec chunk c at FULL CU speed (legacy k_spec body),
//                  publish specDone[c] on a dedicated 256B flag line.
//   block 0      : wave 0 = spec chunk 0 (final row stays in registers);
//                  waves 1..15 = fix chunk c: prestage Sp/Wp+MKT at once,
//                  acquire specDone[c], prestage p*, then the verified
//                  LDS token chain. Release fence per handoff makes all
//                  prior Osp stores agent-visible before fixDone[c].
//   blocks 16..79: unpack consumers (16 px/thread, R2-verified body),
//                  each polls ONE per-chunk fixDone line (<=4 pollers
//                  per line, 1 lane per block, s_sleep backoff).
// 80 blocks, all co-resident (<= capacity); producers never wait on
// consumers -> deadlock-free without cooperative launch.
// Flags are ws-poison-safe: 0xAAAAAAAA != SPEC_DONE/FIX_DONE.
// =====================================================================
__global__ __launch_bounds__(1024) void k_rest(const unsigned int* __restrict__ Sp,
                                               const unsigned int* __restrict__ Wp,
                                               unsigned int* __restrict__ Osp,
                                               float* __restrict__ out,
                                               unsigned int* __restrict__ flags) {
    __shared__ unsigned int ringW[8][32];
    __shared__ unsigned int ringS[8][32];
    __shared__ unsigned int prevLds[16][32];
    __shared__ unsigned int locTok;
    const int tid = threadIdx.x;
    const int b = (int)blockIdx.x;
    unsigned int* specD = flags;                         // 16 lines
    unsigned int* fixD  = flags + 16 * FLAG_STRIDE;      // 16 lines

    if (b >= 16) {
        // ---------------- unpack consumer: 16 rows per block ----------------
        const int bb = b - 15;                           // 1..64
        const unsigned int needChunk = (unsigned int)((16 * bb - 2) >> 6);
        if (tid == 0) {
            const unsigned int* f = fixD + needChunk * FLAG_STRIDE;
            while (__hip_atomic_load(f, __ATOMIC_RELAXED,
                                     __HIP_MEMORY_SCOPE_AGENT) != FIX_DONE)
                __builtin_amdgcn_s_sleep(16);
        }
        __syncthreads();
        __builtin_amdgcn_fence(__ATOMIC_ACQUIRE, "agent");
        const int px = ((bb - 1) * 1024 + tid) * 16;     // 16 px per thread
        unsigned int w = Osp[px >> 5];
        unsigned int bits = (w >> (px & 16)) & 0xFFFFu;
        float4* o = (float4*)(out + px);
        #pragma unroll
        for (int q = 0; q < 4; ++q) {
            float4 v;
            v.x = (bits & (1u << (4 * q + 0))) ? 1.f : 0.f;
            v.y = (bits & (1u << (4 * q + 1))) ? 1.f : 0.f;
            v.z = (bits & (1u << (4 * q + 2))) ? 1.f : 0.f;
            v.w = (bits & (1u << (4 * q + 3))) ? 1.f : 0.f;
            o[q] = v;
        }
        return;
    }

    if (b > 0) {
        // ---------------- spec block: chunk b on its own CU ------------------
        if (tid >= 64) return;                           // wave 0 only; no barriers
        const int lane = tid;
        const int k = lane & 31;
        unsigned int bdUnused;
        SPEC_CHUNK(b, bdUnused)
        (void)bdUnused;
        if (lane == 0)
            __hip_atomic_store(specD + b * FLAG_STRIDE, SPEC_DONE,
                               __ATOMIC_RELEASE, __HIP_MEMORY_SCOPE_AGENT);
        return;
    }

    // ---------------- block 0: spec chunk 0 (wave 0) + fix chain ------------
    const int wv = tid >> 6;
    const int lane = tid & 63;
    const int k = lane & 31;
    if (tid == 0) locTok = 0u;
    __syncthreads();

    if (wv == 0) {
        unsigned int bd;
        SPEC_CHUNK(0, bd)
        prevLds[1][k] = bd;                              // true row 64 (chunk 0 exact)
        __builtin_amdgcn_fence(__ATOMIC_RELEASE, "agent");  // drain Osp stores
        asm volatile("s_waitcnt lgkmcnt(0)" ::: "memory");
        if (lane == 0) *((volatile unsigned int*)&locTok) = 1u;
        if (lane == 0)
            __hip_atomic_store(fixD + 0, FIX_DONE,
                               __ATOMIC_RELEASE, __HIP_MEMORY_SCOPE_AGENT);
        return;
    }

    // waves 1..15: fix chunk c
    const int c = wv;
    const int r0 = c * CH + 1;

    // prestage Sp/Wp + MKT immediately (k_fused products, prior kernel)
    const unsigned int* Sb = Sp + r0 * 32 + k;
    unsigned int S0 = Sb[0],   S1 = Sb[32],  S2 = Sb[64],  S3 = Sb[96],
                 S4 = Sb[128], S5 = Sb[160], S6 = Sb[192], S7 = Sb[224],
                 S8 = Sb[256];
    const unsigned int* Wb = Wp + r0 * 32 + k;
    unsigned int W0 = Wb[0],   W1 = Wb[32],  W2 = Wb[64],  W3 = Wb[96],
                 W4 = Wb[128], W5 = Wb[160], W6 = Wb[192], W7 = Wb[224];
    unsigned int T0, T1, T2, T3, T4, T5, T6, T7;
    MKT(T0, S0, S1) MKT(T1, S1, S2) MKT(T2, S2, S3) MKT(T3, S3, S4)
    MKT(T4, S4, S5) MKT(T5, S5, S6) MKT(T6, S6, S7) MKT(T7, S7, S8)

    // wait for spec block c, then prestage its Osp rows
    {
        const unsigned int* f = specD + c * FLAG_STRIDE;
        while (__hip_atomic_load(f, __ATOMIC_RELAXED,
                                 __HIP_MEMORY_SCOPE_AGENT) != SPEC_DONE)
            __builtin_amdgcn_s_sleep(2);
    }
    __builtin_amdgcn_fence(__ATOMIC_ACQUIRE, "agent");
    const unsigned int* Ob = Osp + r0 * 32 + k;
    unsigned int p0 = Ob[0],   p1 = Ob[32],  p2 = Ob[64],  p3 = Ob[96],
                 p4 = Ob[128], p5 = Ob[160], p6 = Ob[192], p7 = Ob[224];
    int lr = r0 + 63; if (lr > 1022) lr = 1022;
    unsigned int p1last = Osp[lr * 32 + k];

    unsigned int bd = p1last;
    bool done = false, converged = false;
    unsigned int prevU = 0u, crp = 0u;

    // token spin (verified LDS chain)
    while (*((volatile unsigned int*)&locTok) != (unsigned int)c)
        __builtin_amdgcn_s_sleep(1);
    asm volatile("" ::: "memory");
    prevU = prevLds[c][k];                               // true last row of chunk c-1
    {
        unsigned long long mh = __ballot((prevU >> 31) != 0u);
        unsigned long long ml = __ballot((prevU & 1u) != 0u);
        crp = ((((unsigned int)(mh << 1)) >> k) & 1u)
            | (((((unsigned int)(ml >> 1)) >> k) & 1u) << 31);
    }
    FIX_STEP(0, W0, S0, T0, p0) FIX_STEP(1, W1, S1, T1, p1)
    FIX_STEP(2, W2, S2, T2, p2) FIX_STEP(3, W3, S3, T3, p3)
    FIX_STEP(4, W4, S4, T4, p4) FIX_STEP(5, W5, S5, T5, p5)
    FIX_STEP(6, W6, S6, T6, p6) FIX_STEP(7, W7, S7, T7, p7)
    if (!done) {
        #pragma unroll 1
        for (int d = 8; d < CH; ++d) {                   // rare deep path
            int r = r0 + d;
            if (r > 1022) break;
            unsigned int Wv = Wp[r * 32 + k];
            unsigned int Sv = Sp[r * 32 + k];
            int rn = r + 1; if (rn > 1023) rn = 1023;
            unsigned int Sn = Sp[rn * 32 + k];
            unsigned int sp = Osp[r * 32 + k];
            unsigned int Tv;
            MKT(Tv, Sv, Sn)
            CHAIN_STEP(Wv, Sv, Tv)
            unsigned long long df = __ballot(outv != sp);
            if ((df & 0xFFFFFFFFull) == 0ull) { converged = true; break; }
            Osp[r * 32 + k] = outv;
        }
    }
    bd = converged ? p1last : prevU;                     // true row r0+63 either way

    if (c < NW - 1) prevLds[c + 1][k] = bd;
    __builtin_amdgcn_fence(__ATOMIC_RELEASE, "agent");   // drain fix Osp stores
    asm volatile("s_waitcnt lgkmcnt(0)" ::: "memory");
    if (lane == 0) *((volatile unsigned int*)&locTok) = (unsigned int)(c + 1);
    if (lane == 0)
        __hip_atomic_store(fixD + c * FLAG_STRIDE, FIX_DONE,
                           __ATOMIC_RELEASE, __HIP_MEMORY_SCOPE_AGENT);
}

extern "C" void kernel_launch(void* const* d_in, const int* in_sizes, int n_in,
                              void* d_out, int out_size, void* d_ws, size_t ws_size,
                              hipStream_t stream) {
    const float* x = (const float*)d_in[0];
    float* out = (float*)d_out;
    char* ws = (char*)d_ws;

    unsigned long long* Sp = (unsigned long long*)(ws);
    unsigned long long* Wp = (unsigned long long*)(ws + 128u * 1024u);
    unsigned int*      Osp = (unsigned int*)(ws + 256u * 1024u);
    unsigned int*      flags = (unsigned int*)(ws + 1024u * 1024u);
    // flags start 0xAAAAAAAA (ws poison each iteration) -> "not ready";
    // producers write SPEC_DONE/FIX_DONE in dependency order each launch.

    k_fused<<<1024, 256, 0, stream>>>(x, Sp, Wp);
    k_rest<<<80, 1024, 0, stream>>>((const unsigned int*)Sp,
                                    (const unsigned int*)Wp,
                                    Osp, out, flags);
}

// Round 4
// 101.459 us; speedup vs baseline: 2.8588x; 1.0223x over previous
//
#include <hip/hip_runtime.h>
#include <math.h>

#define IH 1024
#define IW 1024
#define NPIX (IH * IW)
#define NW 16   // chunks
#define CH 64   // rows per chunk
#define NWB 8   // worker blocks (2 chunks each)

#define FIX_DONE  0xF1DE0001u
#define TOK_DONE  0x70CEA5E1u
#define FLAG_STRIDE 64   // uints = 256 B between flag lines

// async global->LDS: 64 lanes x 4B = 256 B = TWO consecutive 32-word rows
__device__ __forceinline__ void dma4(const unsigned int* g, unsigned int* l) {
    __builtin_amdgcn_global_load_lds(
        (const __attribute__((address_space(1))) void*)g,
        (__attribute__((address_space(3))) void*)l, 4, 0, 0);
}

// One row of the recurrence (verified absmax 0 since R8).
#define CHAIN_STEP(W_, S_, T_)                                                  \
    unsigned int hxp = (prevU << 1) | prevU | ((prevU >> 1) | crp);             \
    unsigned int seed = hxp | (T_);                                             \
    unsigned int P = (W_);                                                      \
    unsigned int G = (S_) | (P & seed);                                         \
    unsigned int A = G | P;                                                     \
    unsigned int AXG = A ^ G;                                                   \
    unsigned int s1v = A + G;                                                   \
    unsigned long long gm = __ballot(s1v < A) & 0xFFFFFFFFull;                  \
    unsigned long long pm = __ballot(s1v == 0xFFFFFFFFu) & 0xFFFFFFFFull;       \
    unsigned long long G0 = __ballot((G & 1u) != 0u);                           \
    unsigned long long P0 = __ballot((P & 1u) != 0u);                           \
    unsigned long long aa = gm | pm;                                            \
    unsigned long long ssum = aa + gm;                                          \
    unsigned long long cvw = ssum ^ aa ^ gm;                                    \
    unsigned long long mlo_o = G0 | (P0 & cvw);                                 \
    unsigned int cin = (((unsigned int)cvw) >> k) & 1u;                         \
    unsigned int ovb = ((((unsigned int)(cvw >> 1)) >> k) & 1u) << 31;          \
    unsigned int s2 = s1v + cin;                                                \
    unsigned int outv = ((s2 ^ AXG) >> 1) | ovb;                                \
    unsigned int rtP = ((((unsigned int)(mlo_o >> 1)) >> k) & 1u) << 31;        \
    crp = cin | rtP;                                                            \
    prevU = outv;

// STAT_r = Rx(S_r) | Hx(S_{r+1})  (verified)
#define MKT(T_, SA_, SN_) {                                                     \
    unsigned long long mla = __ballot(((SA_) & 1u) != 0u);                      \
    unsigned long long mln = __ballot(((SN_) & 1u) != 0u);                      \
    unsigned long long mhn = __ballot(((SN_) >> 31) != 0u);                     \
    unsigned int rxC = (SA_) | ((SA_) >> 1)                                     \
                     | (((((unsigned int)(mla >> 1)) >> k) & 1u) << 31);        \
    unsigned int hxN = (SN_) | ((SN_) << 1) | ((SN_) >> 1)                      \
                     | ((((unsigned int)(mhn << 1)) >> k) & 1u)                 \
                     | (((((unsigned int)(mln >> 1)) >> k) & 1u) << 31);        \
    T_ = rxC | hxN; }

// ---------------- Stage 1+2+3 fused: gray -> Sobel -> NMS -> bit-packed ------
// (unchanged from the verified 96.5us version)
__global__ __launch_bounds__(256) void k_fused(const float* __restrict__ x,
                                               unsigned long long* __restrict__ Sp,
                                               unsigned long long* __restrict__ Wp) {
    __shared__ float g[20][72];
    __shared__ float m[18][68];
    const int bx = blockIdx.x & 15, by = blockIdx.x >> 4;
    const int tid = threadIdx.x;
    const int gi0 = by * 16 - 2, gj0 = bx * 64 - 2;

    for (int e = tid; e < 20 * 68; e += 256) {
        int ly = e / 68, lx = e - ly * 68;
        int gy = gi0 + ly, gxc = gj0 + lx;
        float v = 0.f;
        if ((unsigned)gy < (unsigned)IH && (unsigned)gxc < (unsigned)IW) {
            int p = gy * IW + gxc;
            float r = x[p], gg = x[NPIX + p], b = x[2 * NPIX + p];
            v = __fadd_rn(__fadd_rn(__fmul_rn(r, 0.2989f), __fmul_rn(gg, 0.587f)),
                          __fmul_rn(b, 0.114f));
        }
        g[ly][lx] = v;
    }
    __syncthreads();

    for (int e = tid; e < 18 * 66; e += 256) {
        int ly = e / 66, lx = e - ly * 66;
        float a00 = g[ly][lx],   a01 = g[ly][lx+1],   a02 = g[ly][lx+2];
        float a10 = g[ly+1][lx],                      a12 = g[ly+1][lx+2];
        float a20 = g[ly+2][lx], a21 = g[ly+2][lx+1], a22 = g[ly+2][lx+2];
        float gx = __fmul_rn(-1.f, a00);
        gx = __fadd_rn(gx, a02);
        gx = __fadd_rn(gx, __fmul_rn(-2.f, a10));
        gx = __fadd_rn(gx, __fmul_rn(2.f, a12));
        gx = __fadd_rn(gx, __fmul_rn(-1.f, a20));
        gx = __fadd_rn(gx, a22);
        float gy = a00;
        gy = __fadd_rn(gy, __fmul_rn(2.f, a01));
        gy = __fadd_rn(gy, a02);
        gy = __fadd_rn(gy, __fmul_rn(-1.f, a20));
        gy = __fadd_rn(gy, __fmul_rn(-2.f, a21));
        gy = __fadd_rn(gy, __fmul_rn(-1.f, a22));
        m[ly][lx] = __fsqrt_rn(__fadd_rn(__fmul_rn(gx, gx), __fmul_rn(gy, gy)));
    }
    __syncthreads();

    const int lane = tid & 63;
    const int wv = tid >> 6;
    #pragma unroll
    for (int rr = 0; rr < 4; ++rr) {
        int ti = wv * 4 + rr;
        int i = by * 16 + ti, j = bx * 64 + lane;
        float a00 = g[ti+1][lane+1], a01 = g[ti+1][lane+2], a02 = g[ti+1][lane+3];
        float a10 = g[ti+2][lane+1],                         a12 = g[ti+2][lane+3];
        float a20 = g[ti+3][lane+1], a21 = g[ti+3][lane+2], a22 = g[ti+3][lane+3];
        float gx = __fmul_rn(-1.f, a00);
        gx = __fadd_rn(gx, a02);
        gx = __fadd_rn(gx, __fmul_rn(-2.f, a10));
        gx = __fadd_rn(gx, __fmul_rn(2.f, a12));
        gx = __fadd_rn(gx, __fmul_rn(-1.f, a20));
        gx = __fadd_rn(gx, a22);
        float gy = a00;
        gy = __fadd_rn(gy, __fmul_rn(2.f, a01));
        gy = __fadd_rn(gy, a02);
        gy = __fadd_rn(gy, __fmul_rn(-1.f, a20));
        gy = __fadd_rn(gy, __fmul_rn(-2.f, a21));
        gy = __fadd_rn(gy, __fmul_rn(-1.f, a22));

        float ai = __fmul_rn(atan2f(gy, gx), 57.295779513082320876798154814105f);
        float c = m[ti+1][lane+1];
        float n1, n2;
        if (ai < -22.5f || ai >= 157.5f)      { n1 = m[ti+1][lane];   n2 = m[ti+1][lane+2]; }
        else if (ai < 22.5f)                  { n1 = m[ti][lane+1];   n2 = m[ti+2][lane+1]; }
        else if (ai < 67.5f)                  { n1 = m[ti][lane];     n2 = m[ti+2][lane+2]; }
        else if (ai < 112.5f)                 { n1 = m[ti][lane+1];   n2 = m[ti+2][lane+1]; }
        else                                  { n1 = m[ti][lane+2];   n2 = m[ti+2][lane];   }
        bool border = (i == 0) | (i == IH - 1) | (j == 0) | (j == IW - 1);
        bool keep = (c >= n1) && (c >= n2);
        float supp = keep ? c : 0.f;
        bool sb = !border && (supp >= 50.f);
        bool wb = !border && (supp >= 20.f) && !(supp >= 50.f);
        unsigned long long bs = __ballot(sb);
        unsigned long long bw = __ballot(wb);
        if (lane == 0) {
            Sp[i * 16 + bx] = bs;
            Wp[i * 16 + bx] = bw;
        }
    }
}

// =====================================================================
// Stage 4+5 fused, R4 layout — the fix chain's working set lives in LDS:
//   blocks 0..7  : worker blocks, 2 chunk-waves each (chunk = 2b+wv).
//                  Each wave dma4-stages its chunk's 64 W rows + 64 S
//                  rows into LDS, runs spec FROM LDS (storing spec out
//                  to Osp and LDS Pl), then runs fix FROM LDS — one
//                  uniform loop, no global deep path. Token chain:
//                  intra-block LDS handoff (verified R2 pattern) and
//                  cross-block release/acquire flags (verified R1/R3).
//   blocks 8..71 : unpack consumers (R3-verified body).
// 72 blocks, all co-resident; producers never wait on consumers.
// Flags ws-poison-safe: 0xAAAAAAAA != FIX_DONE/TOK_DONE.
// =====================================================================
__global__ __launch_bounds__(1024) void k_rest(const unsigned int* __restrict__ Sp,
                                               const unsigned int* __restrict__ Wp,
                                               unsigned int* __restrict__ Osp,
                                               float* __restrict__ out,
                                               unsigned int* __restrict__ flags) {
    __shared__ unsigned int Wl[2][64][32];   // 16 KB
    __shared__ unsigned int Sl[2][64][32];   // 16 KB
    __shared__ unsigned int Pl[2][64][32];   // 16 KB
    __shared__ unsigned int prevLds[32];
    __shared__ unsigned int locTok;
    const int tid = threadIdx.x;
    const int b = (int)blockIdx.x;
    unsigned int* fixD = flags;                          // 16 lines

    if (b >= NWB) {
        // ---------------- unpack consumer: 16 rows per block ----------------
        const int bb = b - (NWB - 1);                    // 1..64
        const unsigned int needChunk = (unsigned int)((16 * bb - 2) >> 6);
        if (tid == 0) {
            const unsigned int* f = fixD + needChunk * FLAG_STRIDE;
            while (__hip_atomic_load(f, __ATOMIC_RELAXED,
                                     __HIP_MEMORY_SCOPE_AGENT) != FIX_DONE)
                __builtin_amdgcn_s_sleep(16);
        }
        __syncthreads();
        __builtin_amdgcn_fence(__ATOMIC_ACQUIRE, "agent");
        const int px = ((bb - 1) * 1024 + tid) * 16;     // 16 px per thread
        unsigned int w = Osp[px >> 5];
        unsigned int bits = (w >> (px & 16)) & 0xFFFFu;
        float4* o = (float4*)(out + px);
        #pragma unroll
        for (int q = 0; q < 4; ++q) {
            float4 v;
            v.x = (bits & (1u << (4 * q + 0))) ? 1.f : 0.f;
            v.y = (bits & (1u << (4 * q + 1))) ? 1.f : 0.f;
            v.z = (bits & (1u << (4 * q + 2))) ? 1.f : 0.f;
            v.w = (bits & (1u << (4 * q + 3))) ? 1.f : 0.f;
            o[q] = v;
        }
        return;
    }

    // ---------------- worker block: chunks 2b (wave 0) and 2b+1 (wave 1) ----
    if (tid == 0) locTok = 0u;
    __syncthreads();                 // all 16 waves participate, then most exit
    if (tid >= 128) return;

    const int wv = tid >> 6;                             // 0..1
    const int lane = tid & 63;
    const int k = lane & 31;
    const int c = 2 * b + wv;                            // chunk 0..15
    const int r0 = c * CH + 1;

    // --- stage full chunk into LDS (W rows r0..r0+63, S rows r0..r0+63) ---
    #pragma unroll
    for (int q = 0; q < 32; ++q) {
        dma4(Wp + (r0 + 2 * q) * 32 + lane, &Wl[wv][2 * q][0]);
        dma4(Sp + (r0 + 2 * q) * 32 + lane, &Sl[wv][2 * q][0]);
    }
    unsigned int prevU = Sp[(r0 - 1) * 32 + k];          // static lower bound
    int tl = r0 + 64; if (tl > 1023) tl = 1023;
    unsigned int Stail = Sp[tl * 32 + k];                // S_{r0+64}
    unsigned int crp;
    {
        unsigned long long mh = __ballot((prevU >> 31) != 0u);
        unsigned long long ml = __ballot((prevU & 1u) != 0u);
        crp = ((((unsigned int)(mh << 1)) >> k) & 1u)
            | (((((unsigned int)(ml >> 1)) >> k) & 1u) << 31);
    }
    if (c == 0 && lane < 32) Osp[k] = 0u;                // border rows
    if (c == NW - 1 && lane < 32) Osp[1023 * 32 + k] = 0u;
    asm volatile("s_waitcnt vmcnt(0)" ::: "memory");     // staging complete

    // --- spec from LDS (verified math; output to Osp AND Pl) ---
    unsigned int SA = Sl[wv][0][k];
    unsigned long long mloA = __ballot((SA & 1u) != 0u);
    #pragma unroll 2
    for (int d = 0; d < 64; ++d) {
        unsigned int Wv = Wl[wv][d][k];
        unsigned int RS = (d < 63) ? Sl[wv][d + 1][k] : Stail;
        unsigned long long mhiN = __ballot((RS >> 31) != 0u);
        unsigned long long mloN = __ballot((RS & 1u) != 0u);
        unsigned int rxC = SA | (SA >> 1)
                         | (((((unsigned int)(mloA >> 1)) >> k) & 1u) << 31);
        unsigned int hxN = RS | (RS << 1) | (RS >> 1)
                         | ((((unsigned int)(mhiN << 1)) >> k) & 1u)
                         | (((((unsigned int)(mloN >> 1)) >> k) & 1u) << 31);
        unsigned int Tv = rxC | hxN;
        CHAIN_STEP(Wv, SA, Tv)
        Pl[wv][d][k] = outv;
        int r = r0 + d;
        if (r <= 1022) Osp[r * 32 + k] = outv;
        SA = RS; mloA = mloN;
    }

    // --- fix from LDS ---
    unsigned int bd;
    bool converged = false;
    if (c == 0) {
        bd = Pl[wv][63][k];                              // chunk 0 spec is exact
    } else {
        // wait for predecessor chunk's true tail row
        if (wv == 0) {                                   // cross-block handoff
            const unsigned int* tok = flags + (16 + b) * FLAG_STRIDE;
            while (__hip_atomic_load(tok, __ATOMIC_RELAXED,
                                     __HIP_MEMORY_SCOPE_AGENT) != TOK_DONE)
                __builtin_amdgcn_s_sleep(1);
            __builtin_amdgcn_fence(__ATOMIC_ACQUIRE, "agent");
            prevU = __hip_atomic_load(flags + (32 + b) * FLAG_STRIDE + k,
                                      __ATOMIC_RELAXED, __HIP_MEMORY_SCOPE_AGENT);
        } else {                                         // intra-block handoff
            while (*((volatile unsigned int*)&locTok) != 1u)
                __builtin_amdgcn_s_sleep(1);
            asm volatile("" ::: "memory");
            prevU = prevLds[k];
        }
        // drain own spec stores before fix re-stores same addresses
        asm volatile("s_waitcnt vmcnt(0)" ::: "memory");
        {
            unsigned long long mh = __ballot((prevU >> 31) != 0u);
            unsigned long long ml = __ballot((prevU & 1u) != 0u);
            crp = ((((unsigned int)(mh << 1)) >> k) & 1u)
                | (((((unsigned int)(ml >> 1)) >> k) & 1u) << 31);
        }
        #pragma unroll 1
        for (int d = 0; d < 64; ++d) {
            int r = r0 + d;
            if (r > 1022) break;
            unsigned int Wv = Wl[wv][d][k];
            unsigned int Sv = Sl[wv][d][k];
            unsigned int Sn = (d < 63) ? Sl[wv][d + 1][k] : Stail;
            unsigned int Tv;
            MKT(Tv, Sv, Sn)
            CHAIN_STEP(Wv, Sv, Tv)
            unsigned long long df = __ballot(outv != Pl[wv][d][k]);
            if ((df & 0xFFFFFFFFull) == 0ull) { converged = true; break; }
            Osp[r * 32 + k] = outv;
        }
        bd = converged ? Pl[wv][63][k] : prevU;          // true row r0+63 either way
    }

    // --- publish: token to successor chunk first (critical path) ---
    if (wv == 0) {
        prevLds[k] = bd;
        asm volatile("s_waitcnt lgkmcnt(0)" ::: "memory");
        if (lane == 0) *((volatile unsigned int*)&locTok) = 1u;
    } else if (b < NWB - 1) {
        __hip_atomic_store(flags + (32 + b + 1) * FLAG_STRIDE + k, bd,
                           __ATOMIC_RELAXED, __HIP_MEMORY_SCOPE_AGENT);
        // release-store: makes gPrev (and prior stores) visible before token
        if (lane == 0)
            __hip_atomic_store(flags + (16 + b + 1) * FLAG_STRIDE, TOK_DONE,
                               __ATOMIC_RELEASE, __HIP_MEMORY_SCOPE_AGENT);
    }
    // --- publish fixDone for unpack consumers (Osp must be visible) ---
    asm volatile("s_waitcnt vmcnt(0)" ::: "memory");
    __builtin_amdgcn_fence(__ATOMIC_RELEASE, "agent");
    if (lane == 0)
        __hip_atomic_store(fixD + c * FLAG_STRIDE, FIX_DONE,
                           __ATOMIC_RELEASE, __HIP_MEMORY_SCOPE_AGENT);
}

extern "C" void kernel_launch(void* const* d_in, const int* in_sizes, int n_in,
                              void* d_out, int out_size, void* d_ws, size_t ws_size,
                              hipStream_t stream) {
    const float* x = (const float*)d_in[0];
    float* out = (float*)d_out;
    char* ws = (char*)d_ws;

    unsigned long long* Sp = (unsigned long long*)(ws);
    unsigned long long* Wp = (unsigned long long*)(ws + 128u * 1024u);
    unsigned int*      Osp = (unsigned int*)(ws + 256u * 1024u);
    unsigned int*      flags = (unsigned int*)(ws + 1024u * 1024u);
    // flags poisoned 0xAAAAAAAA each iteration -> "not ready"; producers
    // write FIX_DONE/TOK_DONE in dependency order each launch.

    k_fused<<<1024, 256, 0, stream>>>(x, Sp, Wp);
    k_rest<<<72, 1024, 0, stream>>>((const unsigned int*)Sp,
                                    (const unsigned int*)Wp,
                                    Osp, out, flags);
}

// Round 5
// 97.641 us; speedup vs baseline: 2.9706x; 1.0391x over previous
//
#include <hip/hip_runtime.h>
#include <math.h>

#define IH 1024
#define IW 1024
#define NPIX (IH * IW)
#define NW 16   // chunks
#define CH 64   // rows per chunk
#define NWB 8   // worker blocks (2 chunks each)

#define FIX_DONE  0xF1DE0001u
#define TOK_DONE  0x70CEA5E1u
#define FLAG_STRIDE 64   // uints = 256 B between flag lines

// Relaxed agent-scope atomics: execute at the coherence point (LLC), so they
// are cross-XCD visible WITHOUT wbl2/inv cache maintenance. This is the whole
// point of R5: no release fences anywhere on the serial chain.
#define AST(p_, v_) __hip_atomic_store((p_), (v_), __ATOMIC_RELAXED, __HIP_MEMORY_SCOPE_AGENT)
#define ALD(p_)     __hip_atomic_load((p_), __ATOMIC_RELAXED, __HIP_MEMORY_SCOPE_AGENT)

// async global->LDS: 64 lanes x 4B = 256 B = TWO consecutive 32-word rows
__device__ __forceinline__ void dma4(const unsigned int* g, unsigned int* l) {
    __builtin_amdgcn_global_load_lds(
        (const __attribute__((address_space(1))) void*)g,
        (__attribute__((address_space(3))) void*)l, 4, 0, 0);
}

// One row of the recurrence (verified absmax 0 since R8).
#define CHAIN_STEP(W_, S_, T_)                                                  \
    unsigned int hxp = (prevU << 1) | prevU | ((prevU >> 1) | crp);             \
    unsigned int seed = hxp | (T_);                                             \
    unsigned int P = (W_);                                                      \
    unsigned int G = (S_) | (P & seed);                                         \
    unsigned int A = G | P;                                                     \
    unsigned int AXG = A ^ G;                                                   \
    unsigned int s1v = A + G;                                                   \
    unsigned long long gm = __ballot(s1v < A) & 0xFFFFFFFFull;                  \
    unsigned long long pm = __ballot(s1v == 0xFFFFFFFFu) & 0xFFFFFFFFull;       \
    unsigned long long G0 = __ballot((G & 1u) != 0u);                           \
    unsigned long long P0 = __ballot((P & 1u) != 0u);                           \
    unsigned long long aa = gm | pm;                                            \
    unsigned long long ssum = aa + gm;                                          \
    unsigned long long cvw = ssum ^ aa ^ gm;                                    \
    unsigned long long mlo_o = G0 | (P0 & cvw);                                 \
    unsigned int cin = (((unsigned int)cvw) >> k) & 1u;                         \
    unsigned int ovb = ((((unsigned int)(cvw >> 1)) >> k) & 1u) << 31;          \
    unsigned int s2 = s1v + cin;                                                \
    unsigned int outv = ((s2 ^ AXG) >> 1) | ovb;                                \
    unsigned int rtP = ((((unsigned int)(mlo_o >> 1)) >> k) & 1u) << 31;        \
    crp = cin | rtP;                                                            \
    prevU = outv;

// STAT_r = Rx(S_r) | Hx(S_{r+1})  (verified)
#define MKT(T_, SA_, SN_) {                                                     \
    unsigned long long mla = __ballot(((SA_) & 1u) != 0u);                      \
    unsigned long long mln = __ballot(((SN_) & 1u) != 0u);                      \
    unsigned long long mhn = __ballot(((SN_) >> 31) != 0u);                     \
    unsigned int rxC = (SA_) | ((SA_) >> 1)                                     \
                     | (((((unsigned int)(mla >> 1)) >> k) & 1u) << 31);        \
    unsigned int hxN = (SN_) | ((SN_) << 1) | ((SN_) >> 1)                      \
                     | ((((unsigned int)(mhn << 1)) >> k) & 1u)                 \
                     | (((((unsigned int)(mln >> 1)) >> k) & 1u) << 31);        \
    T_ = rxC | hxN; }

// ---------------- Stage 1+2+3 fused: gray -> Sobel -> NMS -> bit-packed ------
// (unchanged from the verified 96.5us version)
__global__ __launch_bounds__(256) void k_fused(const float* __restrict__ x,
                                               unsigned long long* __restrict__ Sp,
                                               unsigned long long* __restrict__ Wp) {
    __shared__ float g[20][72];
    __shared__ float m[18][68];
    const int bx = blockIdx.x & 15, by = blockIdx.x >> 4;
    const int tid = threadIdx.x;
    const int gi0 = by * 16 - 2, gj0 = bx * 64 - 2;

    for (int e = tid; e < 20 * 68; e += 256) {
        int ly = e / 68, lx = e - ly * 68;
        int gy = gi0 + ly, gxc = gj0 + lx;
        float v = 0.f;
        if ((unsigned)gy < (unsigned)IH && (unsigned)gxc < (unsigned)IW) {
            int p = gy * IW + gxc;
            float r = x[p], gg = x[NPIX + p], b = x[2 * NPIX + p];
            v = __fadd_rn(__fadd_rn(__fmul_rn(r, 0.2989f), __fmul_rn(gg, 0.587f)),
                          __fmul_rn(b, 0.114f));
        }
        g[ly][lx] = v;
    }
    __syncthreads();

    for (int e = tid; e < 18 * 66; e += 256) {
        int ly = e / 66, lx = e - ly * 66;
        float a00 = g[ly][lx],   a01 = g[ly][lx+1],   a02 = g[ly][lx+2];
        float a10 = g[ly+1][lx],                      a12 = g[ly+1][lx+2];
        float a20 = g[ly+2][lx], a21 = g[ly+2][lx+1], a22 = g[ly+2][lx+2];
        float gx = __fmul_rn(-1.f, a00);
        gx = __fadd_rn(gx, a02);
        gx = __fadd_rn(gx, __fmul_rn(-2.f, a10));
        gx = __fadd_rn(gx, __fmul_rn(2.f, a12));
        gx = __fadd_rn(gx, __fmul_rn(-1.f, a20));
        gx = __fadd_rn(gx, a22);
        float gy = a00;
        gy = __fadd_rn(gy, __fmul_rn(2.f, a01));
        gy = __fadd_rn(gy, a02);
        gy = __fadd_rn(gy, __fmul_rn(-1.f, a20));
        gy = __fadd_rn(gy, __fmul_rn(-2.f, a21));
        gy = __fadd_rn(gy, __fmul_rn(-1.f, a22));
        m[ly][lx] = __fsqrt_rn(__fadd_rn(__fmul_rn(gx, gx), __fmul_rn(gy, gy)));
    }
    __syncthreads();

    const int lane = tid & 63;
    const int wv = tid >> 6;
    #pragma unroll
    for (int rr = 0; rr < 4; ++rr) {
        int ti = wv * 4 + rr;
        int i = by * 16 + ti, j = bx * 64 + lane;
        float a00 = g[ti+1][lane+1], a01 = g[ti+1][lane+2], a02 = g[ti+1][lane+3];
        float a10 = g[ti+2][lane+1],                         a12 = g[ti+2][lane+3];
        float a20 = g[ti+3][lane+1], a21 = g[ti+3][lane+2], a22 = g[ti+3][lane+3];
        float gx = __fmul_rn(-1.f, a00);
        gx = __fadd_rn(gx, a02);
        gx = __fadd_rn(gx, __fmul_rn(-2.f, a10));
        gx = __fadd_rn(gx, __fmul_rn(2.f, a12));
        gx = __fadd_rn(gx, __fmul_rn(-1.f, a20));
        gx = __fadd_rn(gx, a22);
        float gy = a00;
        gy = __fadd_rn(gy, __fmul_rn(2.f, a01));
        gy = __fadd_rn(gy, a02);
        gy = __fadd_rn(gy, __fmul_rn(-1.f, a20));
        gy = __fadd_rn(gy, __fmul_rn(-2.f, a21));
        gy = __fadd_rn(gy, __fmul_rn(-1.f, a22));

        float ai = __fmul_rn(atan2f(gy, gx), 57.295779513082320876798154814105f);
        float c = m[ti+1][lane+1];
        float n1, n2;
        if (ai < -22.5f || ai >= 157.5f)      { n1 = m[ti+1][lane];   n2 = m[ti+1][lane+2]; }
        else if (ai < 22.5f)                  { n1 = m[ti][lane+1];   n2 = m[ti+2][lane+1]; }
        else if (ai < 67.5f)                  { n1 = m[ti][lane];     n2 = m[ti+2][lane+2]; }
        else if (ai < 112.5f)                 { n1 = m[ti][lane+1];   n2 = m[ti+2][lane+1]; }
        else                                  { n1 = m[ti][lane+2];   n2 = m[ti+2][lane];   }
        bool border = (i == 0) | (i == IH - 1) | (j == 0) | (j == IW - 1);
        bool keep = (c >= n1) && (c >= n2);
        float supp = keep ? c : 0.f;
        bool sb = !border && (supp >= 50.f);
        bool wb = !border && (supp >= 20.f) && !(supp >= 50.f);
        unsigned long long bs = __ballot(sb);
        unsigned long long bw = __ballot(wb);
        if (lane == 0) {
            Sp[i * 16 + bx] = bs;
            Wp[i * 16 + bx] = bw;
        }
    }
}

// =====================================================================
// Stage 4+5 fused, R5 = R4 minus fences:
//   * every cross-block value (Osp, bd rows, tokens, fixDone) moves via
//     relaxed AGENT-scope atomics (coherent at LLC; no wbl2/inv needed)
//   * ordering on the chain = s_waitcnt vmcnt(0) before each token
//   * fix row loop software-pipelined (next-row LDS prefetch off-chain)
// Layout identical to R4: blocks 0..7 workers (2 chunk-waves each, W/S/P
// in LDS), blocks 8..71 unpack consumers.
// =====================================================================
__global__ __launch_bounds__(1024) void k_rest(const unsigned int* __restrict__ Sp,
                                               const unsigned int* __restrict__ Wp,
                                               unsigned int* __restrict__ Osp,
                                               float* __restrict__ out,
                                               unsigned int* __restrict__ flags) {
    __shared__ unsigned int Wl[2][64][32];   // 16 KB
    __shared__ unsigned int Sl[2][64][32];   // 16 KB
    __shared__ unsigned int Pl[2][64][32];   // 16 KB
    __shared__ unsigned int prevLds[32];
    __shared__ unsigned int locTok;
    const int tid = threadIdx.x;
    const int b = (int)blockIdx.x;
    unsigned int* fixD = flags;                          // 16 lines

    if (b >= NWB) {
        // ---------------- unpack consumer: 16 rows per block ----------------
        const int bb = b - (NWB - 1);                    // 1..64
        const unsigned int needChunk = (unsigned int)((16 * bb - 2) >> 6);
        if (tid == 0) {
            const unsigned int* f = fixD + needChunk * FLAG_STRIDE;
            while (ALD(f) != FIX_DONE)
                __builtin_amdgcn_s_sleep(8);
        }
        __syncthreads();
        // invalidate any stale clean L2 lines before NORMAL Osp reads
        __builtin_amdgcn_fence(__ATOMIC_ACQUIRE, "agent");
        const int px = ((bb - 1) * 1024 + tid) * 16;     // 16 px per thread
        unsigned int w = Osp[px >> 5];
        unsigned int bits = (w >> (px & 16)) & 0xFFFFu;
        float4* o = (float4*)(out + px);
        #pragma unroll
        for (int q = 0; q < 4; ++q) {
            float4 v;
            v.x = (bits & (1u << (4 * q + 0))) ? 1.f : 0.f;
            v.y = (bits & (1u << (4 * q + 1))) ? 1.f : 0.f;
            v.z = (bits & (1u << (4 * q + 2))) ? 1.f : 0.f;
            v.w = (bits & (1u << (4 * q + 3))) ? 1.f : 0.f;
            o[q] = v;
        }
        return;
    }

    // ---------------- worker block: chunks 2b (wave 0) and 2b+1 (wave 1) ----
    if (tid == 0) locTok = 0u;
    __syncthreads();                 // all 16 waves participate, then most exit
    if (tid >= 128) return;

    const int wv = tid >> 6;                             // 0..1
    const int lane = tid & 63;
    const int k = lane & 31;
    const int c = 2 * b + wv;                            // chunk 0..15
    const int r0 = c * CH + 1;

    // --- stage full chunk into LDS (W rows r0..r0+63, S rows r0..r0+63) ---
    #pragma unroll
    for (int q = 0; q < 32; ++q) {
        dma4(Wp + (r0 + 2 * q) * 32 + lane, &Wl[wv][2 * q][0]);
        dma4(Sp + (r0 + 2 * q) * 32 + lane, &Sl[wv][2 * q][0]);
    }
    unsigned int prevU = Sp[(r0 - 1) * 32 + k];          // static lower bound
    int tl = r0 + 64; if (tl > 1023) tl = 1023;
    unsigned int Stail = Sp[tl * 32 + k];                // S_{r0+64}
    unsigned int crp;
    {
        unsigned long long mh = __ballot((prevU >> 31) != 0u);
        unsigned long long ml = __ballot((prevU & 1u) != 0u);
        crp = ((((unsigned int)(mh << 1)) >> k) & 1u)
            | (((((unsigned int)(ml >> 1)) >> k) & 1u) << 31);
    }
    if (c == 0 && lane < 32) AST(&Osp[k], 0u);           // border rows
    if (c == NW - 1 && lane < 32) AST(&Osp[1023 * 32 + k], 0u);
    asm volatile("s_waitcnt vmcnt(0)" ::: "memory");     // staging complete

    // --- spec from LDS (verified math; output to Osp(atomic) AND Pl) ---
    unsigned int SA = Sl[wv][0][k];
    unsigned long long mloA = __ballot((SA & 1u) != 0u);
    #pragma unroll 2
    for (int d = 0; d < 64; ++d) {
        unsigned int Wv = Wl[wv][d][k];
        unsigned int RS = (d < 63) ? Sl[wv][d + 1][k] : Stail;
        unsigned long long mhiN = __ballot((RS >> 31) != 0u);
        unsigned long long mloN = __ballot((RS & 1u) != 0u);
        unsigned int rxC = SA | (SA >> 1)
                         | (((((unsigned int)(mloA >> 1)) >> k) & 1u) << 31);
        unsigned int hxN = RS | (RS << 1) | (RS >> 1)
                         | ((((unsigned int)(mhiN << 1)) >> k) & 1u)
                         | (((((unsigned int)(mloN >> 1)) >> k) & 1u) << 31);
        unsigned int Tv = rxC | hxN;
        CHAIN_STEP(Wv, SA, Tv)
        Pl[wv][d][k] = outv;
        int r = r0 + d;
        if (r <= 1022) AST(&Osp[r * 32 + k], outv);
        SA = RS; mloA = mloN;
    }

    // --- fix from LDS (software-pipelined row loop) ---
    unsigned int bd;
    bool converged = false;
    if (c == 0) {
        bd = Pl[wv][63][k];                              // chunk 0 spec is exact
    } else {
        // wait for predecessor chunk's true tail row
        if (wv == 0) {                                   // cross-block handoff
            const unsigned int* tok = flags + (16 + b) * FLAG_STRIDE;
            while (ALD(tok) != TOK_DONE)
                __builtin_amdgcn_s_sleep(1);
            prevU = ALD(flags + (32 + b) * FLAG_STRIDE + k);
        } else {                                         // intra-block handoff
            while (*((volatile unsigned int*)&locTok) != 1u)
                __builtin_amdgcn_s_sleep(1);
            asm volatile("" ::: "memory");
            prevU = prevLds[k];
        }
        // drain own spec stores (same-address atomic ordering) before fix stores
        asm volatile("s_waitcnt vmcnt(0)" ::: "memory");
        {
            unsigned long long mh = __ballot((prevU >> 31) != 0u);
            unsigned long long ml = __ballot((prevU & 1u) != 0u);
            crp = ((((unsigned int)(mh << 1)) >> k) & 1u)
                | (((((unsigned int)(ml >> 1)) >> k) & 1u) << 31);
        }
        unsigned int Wc  = Wl[wv][0][k];
        unsigned int Sc  = Sl[wv][0][k];
        unsigned int Snx = Sl[wv][1][k];                 // S_{d+1}
        unsigned int Pc  = Pl[wv][0][k];
        #pragma unroll 1
        for (int d = 0; d < 64; ++d) {
            int r = r0 + d;
            if (r > 1022) break;
            // prefetch row d+1 (independent of the chain -> hides LDS latency)
            unsigned int Wn  = (d < 63) ? Wl[wv][d + 1][k] : 0u;
            unsigned int Sn2 = (d < 62) ? Sl[wv][d + 2][k] : Stail;
            unsigned int Pn  = (d < 63) ? Pl[wv][d + 1][k] : 0u;
            unsigned int Tv;
            MKT(Tv, Sc, Snx)
            CHAIN_STEP(Wc, Sc, Tv)
            unsigned long long df = __ballot(outv != Pc);
            if ((df & 0xFFFFFFFFull) == 0ull) { converged = true; break; }
            AST(&Osp[r * 32 + k], outv);
            Wc = Wn; Sc = Snx; Snx = Sn2; Pc = Pn;
        }
        bd = converged ? Pl[wv][63][k] : prevU;          // true row r0+63 either way
    }

    // --- publish: token to successor chunk first (critical path) ---
    if (wv == 0) {
        prevLds[k] = bd;
        asm volatile("s_waitcnt lgkmcnt(0)" ::: "memory");
        if (lane == 0) *((volatile unsigned int*)&locTok) = 1u;
    } else if (b < NWB - 1) {
        AST(flags + (32 + b + 1) * FLAG_STRIDE + k, bd);
        asm volatile("s_waitcnt vmcnt(0)" ::: "memory"); // bd at coherence point
        if (lane == 0)
            AST(flags + (16 + b + 1) * FLAG_STRIDE, TOK_DONE);
    }
    // --- publish fixDone for unpack consumers (all Osp atomics retired) ---
    asm volatile("s_waitcnt vmcnt(0)" ::: "memory");
    if (lane == 0)
        AST(fixD + c * FLAG_STRIDE, FIX_DONE);
}

extern "C" void kernel_launch(void* const* d_in, const int* in_sizes, int n_in,
                              void* d_out, int out_size, void* d_ws, size_t ws_size,
                              hipStream_t stream) {
    const float* x = (const float*)d_in[0];
    float* out = (float*)d_out;
    char* ws = (char*)d_ws;

    unsigned long long* Sp = (unsigned long long*)(ws);
    unsigned long long* Wp = (unsigned long long*)(ws + 128u * 1024u);
    unsigned int*      Osp = (unsigned int*)(ws + 256u * 1024u);
    unsigned int*      flags = (unsigned int*)(ws + 1024u * 1024u);
    // flags poisoned 0xAAAAAAAA each iteration -> "not ready"; producers
    // write FIX_DONE/TOK_DONE in dependency order each launch.

    k_fused<<<1024, 256, 0, stream>>>(x, Sp, Wp);
    k_rest<<<72, 1024, 0, stream>>>((const unsigned int*)Sp,
                                    (const unsigned int*)Wp,
                                    Osp, out, flags);
}